// Round 7
// baseline (883.247 us; speedup 1.0000x reference)
//
#include <hip/hip_runtime.h>
#include <hip/hip_bf16.h>
#include <hip/hip_fp16.h>

#define N_NODES 50000
#define N_EDGES 500000
#define HEADS 8
#define HID 64
#define HD 512   // HEADS*HID
#define NCLS 10
#define M_PAD 50048  // 391*128, GEMM M padded to tile

typedef _Float16 f16x8 __attribute__((ext_vector_type(8)));
typedef _Float16 h8v   __attribute__((ext_vector_type(8)));
typedef float    f32x4 __attribute__((ext_vector_type(4)));

#define GLD_LDS16(g, l) __builtin_amdgcn_global_load_lds( \
    (__attribute__((address_space(1))) void*)(g),         \
    (__attribute__((address_space(3))) void*)(l), 16, 0, 0)

// ---------------------------------------------------------------------------
// fc projection, both node types in one launch: tiled fp32 GEMM 64x64, BK=16
// ---------------------------------------------------------------------------
#define T0_TILES 469  // ceil(30000/64)
#define T1_TILES 313  // ceil(20000/64)
__global__ __launch_bounds__(256) void fc_gemm(const float* __restrict__ A0,
                                               const float* __restrict__ B0,
                                               const float* __restrict__ bias0,
                                               const float* __restrict__ A1,
                                               const float* __restrict__ B1,
                                               const float* __restrict__ bias1,
                                               _Float16* __restrict__ Cb) {
    __shared__ float As[16][68];
    __shared__ float Bs[16][68];
    int bid = blockIdx.x;
    const float* A; const float* B; const float* bias;
    int M, K, row_off, m0;
    if (bid < T0_TILES) { A = A0; B = B0; bias = bias0; M = 30000; K = 256; row_off = 0;     m0 = bid * 64; }
    else                { A = A1; B = B1; bias = bias1; M = 20000; K = 128; row_off = 30000; m0 = (bid - T0_TILES) * 64; }
    int tid = threadIdx.x;
    int tx = tid & 15, ty = tid >> 4;
    float acc[4][4] = {};
    int arow = tid >> 2;
    int akq  = (tid & 3) * 4;
    int brow = tid >> 4;
    int bcol = (tid & 15) * 4;
    for (int k0 = 0; k0 < K; k0 += 16) {
        int m = m0 + arow;
        float4 av = make_float4(0.f, 0.f, 0.f, 0.f);
        if (m < M) av = *(const float4*)(A + (size_t)m * K + k0 + akq);
        As[akq + 0][arow] = av.x; As[akq + 1][arow] = av.y;
        As[akq + 2][arow] = av.z; As[akq + 3][arow] = av.w;
        float4 bv = *(const float4*)(B + (size_t)(k0 + brow) * 64 + bcol);
        *(float4*)(&Bs[brow][bcol]) = bv;
        __syncthreads();
#pragma unroll
        for (int k = 0; k < 16; k++) {
            float4 a = *(const float4*)(&As[k][ty * 4]);
            float4 b = *(const float4*)(&Bs[k][tx * 4]);
            float av4[4] = {a.x, a.y, a.z, a.w};
            float bv4[4] = {b.x, b.y, b.z, b.w};
#pragma unroll
            for (int i = 0; i < 4; i++)
#pragma unroll
                for (int j = 0; j < 4; j++) acc[i][j] += av4[i] * bv4[j];
        }
        __syncthreads();
    }
#pragma unroll
    for (int i = 0; i < 4; i++) {
        int m = m0 + ty * 4 + i;
        if (m < M) {
#pragma unroll
            for (int j = 0; j < 4; j++) {
                int col = tx * 4 + j;
                Cb[(size_t)(row_off + m) * 64 + col] = (_Float16)(acc[i][j] + bias[col]);
            }
        }
    }
}

// ---------------------------------------------------------------------------
// CSR build: count -> parallel scan (3 kernels) -> scatter
// ---------------------------------------------------------------------------
#define NBLK_SCAN 196  // ceil(50000/256)

__global__ void count_kernel(const int* __restrict__ dst, int* __restrict__ cnt) {
    int t = blockIdx.x * blockDim.x + threadIdx.x;
    if (t < N_EDGES) atomicAdd(&cnt[dst[t]], 1);
}

__global__ void scan_part(const int* __restrict__ cnt, int* __restrict__ part) {
    __shared__ int s[256];
    int i = blockIdx.x * 256 + threadIdx.x;
    s[threadIdx.x] = (i < N_NODES) ? cnt[i] : 0;
    __syncthreads();
    for (int off = 128; off; off >>= 1) {
        if (threadIdx.x < off) s[threadIdx.x] += s[threadIdx.x + off];
        __syncthreads();
    }
    if (threadIdx.x == 0) part[blockIdx.x] = s[0];
}

__global__ void scan_offs(int* __restrict__ part) {
    __shared__ int s[256];
    int tid = threadIdx.x;
    int v = (tid < NBLK_SCAN) ? part[tid] : 0;
    s[tid] = v;
    __syncthreads();
    for (int off = 1; off < 256; off <<= 1) {
        int x = (tid >= off) ? s[tid - off] : 0;
        __syncthreads();
        s[tid] += x;
        __syncthreads();
    }
    if (tid < NBLK_SCAN) part[tid] = s[tid] - v;  // exclusive
}

__global__ void scan_apply(const int* __restrict__ cnt, const int* __restrict__ part,
                           int* __restrict__ rp, int* __restrict__ cur) {
    __shared__ int s[256];
    int tid = threadIdx.x;
    int i = blockIdx.x * 256 + tid;
    int v = (i < N_NODES) ? cnt[i] : 0;
    s[tid] = v;
    __syncthreads();
    for (int off = 1; off < 256; off <<= 1) {
        int x = (tid >= off) ? s[tid - off] : 0;
        __syncthreads();
        s[tid] += x;
        __syncthreads();
    }
    if (i < N_NODES) {
        int excl = s[tid] - v + part[blockIdx.x];
        rp[i] = excl; cur[i] = excl;
    }
    if (i == 0) rp[N_NODES] = N_EDGES;
}

__global__ void scatter_kernel(const int* __restrict__ src, const int* __restrict__ dst,
                               int* __restrict__ cursor, int* __restrict__ src_sorted) {
    int t = blockIdx.x * blockDim.x + threadIdx.x;
    if (t >= N_EDGES) return;
    int pos = atomicAdd(&cursor[dst[t]], 1);
    src_sorted[pos] = src[t];
}

// ---------------------------------------------------------------------------
// degree sort: perm[] = node ids ordered by in-degree (counting sort, 64 bins)
// -> waves within an attn_agg block get near-equal trip counts
// ---------------------------------------------------------------------------
__global__ void deg_hist(const int* __restrict__ rp, int* __restrict__ hist) {
    int n = blockIdx.x * blockDim.x + threadIdx.x;
    if (n >= N_NODES) return;
    int d = rp[n + 1] - rp[n]; if (d > 63) d = 63;
    atomicAdd(&hist[d], 1);
}

__global__ void deg_scan(int* __restrict__ hist, int* __restrict__ dcur) {
    if (threadIdx.x == 0) {
        int s = 0;
        for (int i = 0; i < 64; i++) { int v = hist[i]; dcur[i] = s; s += v; }
    }
}

__global__ void deg_scatter(const int* __restrict__ rp, int* __restrict__ dcur,
                            int* __restrict__ perm) {
    int n = blockIdx.x * blockDim.x + threadIdx.x;
    if (n >= N_NODES) return;
    int d = rp[n + 1] - rp[n]; if (d > 63) d = 63;
    int pos = atomicAdd(&dcur[d], 1);
    perm[pos] = n;
}

// ---------------------------------------------------------------------------
// weight transpose+cast (both weights, one launch): Wt[n][k] = f16(W[k][n])
// ---------------------------------------------------------------------------
__global__ void wtrans(const float* __restrict__ W0, const float* __restrict__ W1,
                       _Float16* __restrict__ W0t, _Float16* __restrict__ W1t) {
    int t = blockIdx.x * blockDim.x + threadIdx.x;
    if (t < 64 * 512) {
        int n = t >> 6, k = t & 63;
        W0t[t] = (_Float16)W0[k * 512 + n];
    } else {
        int u = t - 64 * 512;
        if (u >= 512 * 512) return;
        int n = u >> 9, k = u & 511;
        W1t[u] = (_Float16)W1[k * 512 + n];
    }
}

// ---------------------------------------------------------------------------
// f16 MFMA GEMM (R4-proven shape): 128x128 tile, BK=32, XOR-4 kgroup swizzle.
// Fused epilogue: el/er per (row, head); each wave's 64 cols = 1 head.
// ---------------------------------------------------------------------------
__global__ __launch_bounds__(256) void gemm_mfma(const _Float16* __restrict__ A,
                                                 const _Float16* __restrict__ Bt,
                                                 _Float16* __restrict__ Cb,
                                                 const float* __restrict__ al,
                                                 const float* __restrict__ ar,
                                                 float* __restrict__ el,
                                                 float* __restrict__ er,
                                                 int M, int N, int K) {
    __shared__ _Float16 Asl[128 * 32];
    __shared__ _Float16 Bsl[128 * 32];
    int t = threadIdx.x;
    int m0 = blockIdx.y * 128, n0 = blockIdx.x * 128;
    int lane = t & 63;
    int w = t >> 6;
    int wm = (w & 1) * 64, wn = (w >> 1) * 64;
    int l15 = lane & 15, quad = lane >> 4;
    f32x4 acc[4][4];
#pragma unroll
    for (int i = 0; i < 4; i++)
#pragma unroll
        for (int j = 0; j < 4; j++) acc[i][j] = (f32x4){0.f, 0.f, 0.f, 0.f};

    int fb0 = t * 16;
    int fb1 = fb0 + 4096;
    int row0 = fb0 >> 6, kg0 = ((fb0 >> 4) & 3) ^ (row0 & 3);
    int row1 = fb1 >> 6, kg1 = ((fb1 >> 4) & 3) ^ (row1 & 3);

    for (int k0 = 0; k0 < K; k0 += 32) {
        GLD_LDS16(A + (size_t)(m0 + row0) * K + k0 + kg0 * 8, (char*)Asl + fb0);
        GLD_LDS16(A + (size_t)(m0 + row1) * K + k0 + kg1 * 8, (char*)Asl + fb1);
        GLD_LDS16(Bt + (size_t)(n0 + row0) * K + k0 + kg0 * 8, (char*)Bsl + fb0);
        GLD_LDS16(Bt + (size_t)(n0 + row1) * K + k0 + kg1 * 8, (char*)Bsl + fb1);
        __syncthreads();
        f16x8 af[4], bfr[4];
#pragma unroll
        for (int i = 0; i < 4; i++) {
            int r = wm + i * 16 + l15;
            int kg = quad ^ (r & 3);
            af[i] = *(const f16x8*)(Asl + r * 32 + kg * 8);
        }
#pragma unroll
        for (int j = 0; j < 4; j++) {
            int r = wn + j * 16 + l15;
            int kg = quad ^ (r & 3);
            bfr[j] = *(const f16x8*)(Bsl + r * 32 + kg * 8);
        }
#pragma unroll
        for (int i = 0; i < 4; i++)
#pragma unroll
            for (int j = 0; j < 4; j++)
                acc[i][j] = __builtin_amdgcn_mfma_f32_16x16x32_f16(af[i], bfr[j], acc[i][j], 0, 0, 0);
        __syncthreads();
    }
#pragma unroll
    for (int i = 0; i < 4; i++) {
        int rbase = m0 + wm + i * 16 + quad * 4;
#pragma unroll
        for (int j = 0; j < 4; j++) {
            int col = n0 + wn + j * 16 + l15;
#pragma unroll
            for (int r = 0; r < 4; r++) {
                int row = rbase + r;
                if (row < M) Cb[(size_t)row * N + col] = (_Float16)acc[i][j][r];
            }
        }
    }
    int h = (n0 + wn) >> 6;
    float alv[4], arv[4];
#pragma unroll
    for (int j = 0; j < 4; j++) {
        alv[j] = al[h * 64 + j * 16 + l15];
        arv[j] = ar[h * 64 + j * 16 + l15];
    }
#pragma unroll
    for (int i = 0; i < 4; i++) {
#pragma unroll
        for (int r = 0; r < 4; r++) {
            float sl = 0.f, sr = 0.f;
#pragma unroll
            for (int j = 0; j < 4; j++) {
                float v = acc[i][j][r];
                sl += v * alv[j]; sr += v * arv[j];
            }
#pragma unroll
            for (int mk = 1; mk < 16; mk <<= 1) {
                sl += __shfl_xor(sl, mk);
                sr += __shfl_xor(sr, mk);
            }
            int row = m0 + wm + i * 16 + quad * 4 + r;
            if (l15 == 0 && row < M) {
                el[row * HEADS + h] = sl;
                er[row * HEADS + h] = sr;
            }
        }
    }
}

// ---------------------------------------------------------------------------
// Fused edge softmax + aggregation, wave per dst node (degree-sorted order).
// Phase A (lanes=edges): softmax all 8 heads, pre-scaled alpha -> LDS.
// Phase B (lanes=dims): one dwordx4 per edge = full 1KB row; packed f16 FMA.
// ---------------------------------------------------------------------------
__global__ __launch_bounds__(256) void attn_agg(
        const int* __restrict__ rp, const int* __restrict__ srcs,
        const int* __restrict__ perm,
        const float* __restrict__ el, const float* __restrict__ er,
        const _Float16* __restrict__ feat, const float* __restrict__ bias,
        _Float16* __restrict__ out) {
    __shared__ float aS[4][592];   // [0..575] alpha (p*9+h), [576..583] inv, [584..591] m
    __shared__ int   sS[4][64];
    int lane = threadIdx.x & 63;
    int w    = threadIdx.x >> 6;
    int n    = perm[blockIdx.x * 4 + w];
    int s0 = rp[n], s1 = rp[n + 1];
    int deg = s1 - s0;
    float er8[8];
    {
        f32x4 a = *(const f32x4*)(er + (size_t)n * 8);
        f32x4 b = *(const f32x4*)(er + (size_t)n * 8 + 4);
        er8[0]=a[0]; er8[1]=a[1]; er8[2]=a[2]; er8[3]=a[3];
        er8[4]=b[0]; er8[5]=b[1]; er8[6]=b[2]; er8[7]=b[3];
    }
    bool fast = (deg <= 64);
    if (fast) {
        bool act = lane < deg;
        int sp = act ? srcs[s0 + lane] : 0;
        sS[w][lane] = sp;
        f32x4 ea = {0.f,0.f,0.f,0.f}, eb = {0.f,0.f,0.f,0.f};
        if (act) {
            ea = *(const f32x4*)(el + (size_t)sp * 8);
            eb = *(const f32x4*)(el + (size_t)sp * 8 + 4);
        }
        float e8[8] = {ea[0],ea[1],ea[2],ea[3],eb[0],eb[1],eb[2],eb[3]};
#pragma unroll
        for (int h = 0; h < 8; h++) {
            float e = e8[h] + er8[h];
            e = e > 0.f ? e : 0.2f * e;
            e8[h] = act ? e : -1e30f;
        }
#pragma unroll
        for (int h = 0; h < 8; h++) {
            float mm = e8[h];
#pragma unroll
            for (int mk = 1; mk < 64; mk <<= 1) mm = fmaxf(mm, __shfl_xor(mm, mk));
            float pv = act ? __expf(e8[h] - mm) : 0.f;
            float ss = pv;
#pragma unroll
            for (int mk = 1; mk < 64; mk <<= 1) ss += __shfl_xor(ss, mk);
            aS[w][lane * 9 + h] = pv * (1.f / fmaxf(ss, 1e-9f));  // pre-scaled alpha
        }
    } else {
        float m8[8], s8[8];
#pragma unroll
        for (int h = 0; h < 8; h++) { m8[h] = -1e30f; s8[h] = 0.f; }
        for (int base = s0; base < s1; base += 64) {
            bool act = base + lane < s1;
            int sp = act ? srcs[base + lane] : 0;
            f32x4 ea = {0.f,0.f,0.f,0.f}, eb = {0.f,0.f,0.f,0.f};
            if (act) {
                ea = *(const f32x4*)(el + (size_t)sp * 8);
                eb = *(const f32x4*)(el + (size_t)sp * 8 + 4);
            }
            float ev[8] = {ea[0],ea[1],ea[2],ea[3],eb[0],eb[1],eb[2],eb[3]};
#pragma unroll
            for (int h = 0; h < 8; h++) {
                float e = ev[h] + er8[h];
                e = e > 0.f ? e : 0.2f * e;
                e = act ? e : -1e30f;
                float cm = e;
#pragma unroll
                for (int mk = 1; mk < 64; mk <<= 1) cm = fmaxf(cm, __shfl_xor(cm, mk));
                float nm = fmaxf(m8[h], cm);
                float pv = act ? __expf(e - nm) : 0.f;
#pragma unroll
                for (int mk = 1; mk < 64; mk <<= 1) pv += __shfl_xor(pv, mk);
                s8[h] = s8[h] * __expf(m8[h] - nm) + pv;
                m8[h] = nm;
            }
        }
        if (lane == 0) {
#pragma unroll
            for (int h = 0; h < 8; h++) {
                aS[w][576 + h] = 1.f / fmaxf(s8[h], 1e-9f);
                aS[w][584 + h] = m8[h];
            }
        }
    }
    __syncthreads();
    int hh = lane >> 3, d0 = (lane & 7) * 8;   // lane*8 = hh*64 + d0
    h8v acc8 = {(_Float16)0, (_Float16)0, (_Float16)0, (_Float16)0,
                (_Float16)0, (_Float16)0, (_Float16)0, (_Float16)0};
    const _Float16* colbase = feat + hh * 64 + d0;
    if (fast) {
        for (int p = 0; p < deg; p++) {
            int sp = sS[w][p];
            _Float16 ah = (_Float16)aS[w][p * 9 + hh];
            h8v a8 = {ah, ah, ah, ah, ah, ah, ah, ah};
            h8v f = *(const h8v*)(colbase + (size_t)sp * HD);
            acc8 += a8 * f;   // v_pk_fma_f16 x4
        }
    } else {
        float inv_l = aS[w][576 + hh];
        float m_l   = aS[w][584 + hh];
        float ern_l = er[(size_t)n * 8 + hh];
        for (int p = s0; p < s1; p++) {
            int sp = srcs[p];
            float e = el[(size_t)sp * 8 + hh] + ern_l;
            e = e > 0.f ? e : 0.2f * e;
            _Float16 ah = (_Float16)(__expf(e - m_l) * inv_l);
            h8v a8 = {ah, ah, ah, ah, ah, ah, ah, ah};
            h8v f = *(const h8v*)(colbase + (size_t)sp * HD);
            acc8 += a8 * f;
        }
    }
    float4 b0v = *(const float4*)(bias + lane * 8);
    float4 b1v = *(const float4*)(bias + lane * 8 + 4);
    float bb[8] = {b0v.x,b0v.y,b0v.z,b0v.w,b1v.x,b1v.y,b1v.z,b1v.w};
    h8v o;
#pragma unroll
    for (int j = 0; j < 8; j++) {
        float x = (float)acc8[j] + bb[j];
        x = x > 0.f ? x : __expf(x) - 1.f;
        o[j] = (_Float16)x;
    }
    *(h8v*)(out + (size_t)n * HD + lane * 8) = o;
}

// ---------------------------------------------------------------------------
// layer 2 GEMM (N=10) from f16 A, fused el2/er2 epilogue
// ---------------------------------------------------------------------------
__global__ __launch_bounds__(256) void gemm_n10v2(
        const _Float16* __restrict__ A, const float* __restrict__ B,
        const float* __restrict__ al2, const float* __restrict__ ar2,
        float* __restrict__ C, float* __restrict__ el, float* __restrict__ er) {
    __shared__ float Bs[512 * 11];
    int t = threadIdx.x;
    for (int i = t; i < 512 * NCLS; i += 256) {
        int k = i / NCLS, c = i - k * NCLS;
        Bs[k * 11 + c] = B[i];
    }
    __syncthreads();
    int lane = t & 63;
    int m = blockIdx.x * 4 + (t >> 6);
    float acc[NCLS];
#pragma unroll
    for (int c = 0; c < NCLS; c++) acc[c] = 0.f;
    const _Float16* a = A + (size_t)m * HD;
#pragma unroll
    for (int j = 0; j < 8; j++) {
        float av = (float)a[j * 64 + lane];
        const float* br = Bs + (j * 64 + lane) * 11;
#pragma unroll
        for (int c = 0; c < NCLS; c++) acc[c] += av * br[c];
    }
#pragma unroll
    for (int c = 0; c < NCLS; c++)
#pragma unroll
        for (int mk = 1; mk < 64; mk <<= 1) acc[c] += __shfl_xor(acc[c], mk);
    if (lane == 0) {
        float e1 = 0.f, e2 = 0.f;
#pragma unroll
        for (int c = 0; c < NCLS; c++) { e1 += acc[c] * al2[c]; e2 += acc[c] * ar2[c]; }
        el[m] = e1; er[m] = e2;
#pragma unroll
        for (int c = 0; c < NCLS; c++) C[(size_t)m * NCLS + c] = acc[c];
    }
}

// ---------------------------------------------------------------------------
// layer 2 fused softmax+aggregation (H=1, D=10), wave per dst node (sorted)
// ---------------------------------------------------------------------------
__global__ __launch_bounds__(256) void attn2_agg2(
        const int* __restrict__ rp, const int* __restrict__ srcs,
        const int* __restrict__ perm,
        const float* __restrict__ el, const float* __restrict__ er,
        const float* __restrict__ feat2, const float* __restrict__ b2,
        float* __restrict__ out) {
    int lane = threadIdx.x & 63;
    int n = perm[blockIdx.x * 4 + (threadIdx.x >> 6)];
    int s0 = rp[n], s1 = rp[n + 1], deg = s1 - s0;
    float ern = er[n];
    float facc[NCLS];
#pragma unroll
    for (int c = 0; c < NCLS; c++) facc[c] = 0.f;
    if (deg <= 64) {
        bool act = lane < deg;
        int sp = act ? srcs[s0 + lane] : 0;
        float e = act ? el[sp] + ern : 0.f;
        e = e > 0.f ? e : 0.2f * e;
        if (!act) e = -1e30f;
        float mm = e;
#pragma unroll
        for (int mk = 1; mk < 64; mk <<= 1) mm = fmaxf(mm, __shfl_xor(mm, mk));
        float pv = act ? __expf(e - mm) : 0.f;
        float ss = pv;
#pragma unroll
        for (int mk = 1; mk < 64; mk <<= 1) ss += __shfl_xor(ss, mk);
        float a = pv / fmaxf(ss, 1e-9f);
        if (act) {
#pragma unroll
            for (int c = 0; c < NCLS; c++) facc[c] = a * feat2[(size_t)sp * NCLS + c];
        }
    } else {
        float mm = -1e30f, ssum = 0.f;
        for (int base = s0; base < s1; base += 64) {
            bool act = base + lane < s1;
            int sp = act ? srcs[base + lane] : 0;
            float e = act ? el[sp] + ern : 0.f;
            e = e > 0.f ? e : 0.2f * e;
            if (!act) e = -1e30f;
            float cm = e;
#pragma unroll
            for (int mk = 1; mk < 64; mk <<= 1) cm = fmaxf(cm, __shfl_xor(cm, mk));
            float nm = fmaxf(mm, cm);
            float pv = act ? __expf(e - nm) : 0.f;
#pragma unroll
            for (int mk = 1; mk < 64; mk <<= 1) pv += __shfl_xor(pv, mk);
            ssum = ssum * __expf(mm - nm) + pv;
            mm = nm;
        }
        float inv = 1.f / fmaxf(ssum, 1e-9f);
        for (int base = s0; base < s1; base += 64) {
            bool act = base + lane < s1;
            int sp = act ? srcs[base + lane] : 0;
            float e = act ? el[sp] + ern : 0.f;
            e = e > 0.f ? e : 0.2f * e;
            float a = act ? __expf(e - mm) * inv : 0.f;
            if (act) {
#pragma unroll
                for (int c = 0; c < NCLS; c++) facc[c] += a * feat2[(size_t)sp * NCLS + c];
            }
        }
    }
#pragma unroll
    for (int c = 0; c < NCLS; c++)
#pragma unroll
        for (int mk = 1; mk < 64; mk <<= 1) facc[c] += __shfl_xor(facc[c], mk);
    if (lane == 0) {
#pragma unroll
        for (int c = 0; c < NCLS; c++) out[(size_t)n * NCLS + c] = facc[c] + b2[c];
    }
}

// ---------------------------------------------------------------------------
extern "C" void kernel_launch(void* const* d_in, const int* in_sizes, int n_in,
                              void* d_out, int out_size, void* d_ws, size_t ws_size,
                              hipStream_t stream) {
    const float* feat0 = (const float*)d_in[0];
    const float* feat1 = (const float*)d_in[1];
    const float* fc0_w = (const float*)d_in[2];
    const float* fc0_b = (const float*)d_in[3];
    const float* fc1_w = (const float*)d_in[4];
    const float* fc1_b = (const float*)d_in[5];
    const float* W0    = (const float*)d_in[6];
    const float* al0   = (const float*)d_in[7];
    const float* ar0   = (const float*)d_in[8];
    const float* b0    = (const float*)d_in[9];
    const float* W1    = (const float*)d_in[10];
    const float* al1   = (const float*)d_in[11];
    const float* ar1   = (const float*)d_in[12];
    const float* b1    = (const float*)d_in[13];
    const float* W2    = (const float*)d_in[14];
    const float* al2   = (const float*)d_in[15];
    const float* ar2   = (const float*)d_in[16];
    const float* b2    = (const float*)d_in[17];
    const int* eidx    = (const int*)d_in[18];
    const int* src = eidx;
    const int* dst = eidx + N_EDGES;
    float* out = (float*)d_out;

    char* ws = (char*)d_ws;
    size_t off = 0;
    auto alloc = [&](size_t bytes) { size_t o = off; off = (off + bytes + 255) & ~(size_t)255; return o; };

    _Float16* featA = (_Float16*)(ws + alloc((size_t)M_PAD * HD * 2));
    _Float16* aggh  = (_Float16*)(ws + alloc((size_t)M_PAD * HD * 2));
    _Float16* h0h   = (_Float16*)(ws + alloc((size_t)M_PAD * 64 * 2));
    float*    feat2 = (float*)(ws + alloc((size_t)N_NODES * NCLS * 4));
    float*    el    = (float*)(ws + alloc((size_t)N_NODES * HEADS * 4));
    float*    er    = (float*)(ws + alloc((size_t)N_NODES * HEADS * 4));
    int*      cnt   = (int*)  (ws + alloc((size_t)N_NODES * 4));
    int*      rp    = (int*)  (ws + alloc((size_t)(N_NODES + 1) * 4));
    int*      cur   = (int*)  (ws + alloc((size_t)N_NODES * 4));
    int*      srcs  = (int*)  (ws + alloc((size_t)N_EDGES * 4));
    int*      part  = (int*)  (ws + alloc(1024));
    int*      hist  = (int*)  (ws + alloc(256));
    int*      dcur  = (int*)  (ws + alloc(256));
    int*      perm  = (int*)  (ws + alloc((size_t)N_NODES * 4));
    _Float16* W0t   = (_Float16*)(ws + alloc(512 * 64 * 2));
    _Float16* W1t   = (_Float16*)(ws + alloc(512 * 512 * 2));

    // --- fc projection (both types, one launch) ---
    fc_gemm<<<T0_TILES + T1_TILES, 256, 0, stream>>>(feat0, fc0_w, fc0_b,
                                                     feat1, fc1_w, fc1_b, h0h);
    // --- weight transpose+cast (one launch) ---
    wtrans<<<(64 * 512 + 512 * 512 + 255) / 256, 256, 0, stream>>>(W0, W1, W0t, W1t);

    // --- CSR build ---
    hipMemsetAsync(cnt, 0, N_NODES * sizeof(int), stream);
    hipMemsetAsync(hist, 0, 64 * sizeof(int), stream);
    count_kernel<<<(N_EDGES + 255) / 256, 256, 0, stream>>>(dst, cnt);
    scan_part<<<NBLK_SCAN, 256, 0, stream>>>(cnt, part);
    scan_offs<<<1, 256, 0, stream>>>(part);
    scan_apply<<<NBLK_SCAN, 256, 0, stream>>>(cnt, part, rp, cur);
    scatter_kernel<<<(N_EDGES + 255) / 256, 256, 0, stream>>>(src, dst, cur, srcs);

    // --- degree sort (counting sort into perm) ---
    deg_hist<<<NBLK_SCAN, 256, 0, stream>>>(rp, hist);
    deg_scan<<<1, 64, 0, stream>>>(hist, dcur);
    deg_scatter<<<NBLK_SCAN, 256, 0, stream>>>(rp, dcur, perm);

    dim3 ggrid(HD / 128, M_PAD / 128);  // (4, 391)

    // --- layer 0 ---
    gemm_mfma<<<ggrid, 256, 0, stream>>>(h0h, W0t, featA, al0, ar0, el, er,
                                         N_NODES, HD, 64);
    attn_agg<<<N_NODES / 4, 256, 0, stream>>>(rp, srcs, perm, el, er, featA, b0, aggh);

    // --- layer 1 ---
    gemm_mfma<<<ggrid, 256, 0, stream>>>(aggh, W1t, featA, al1, ar1, el, er,
                                         N_NODES, HD, HD);
    attn_agg<<<N_NODES / 4, 256, 0, stream>>>(rp, srcs, perm, el, er, featA, b1, aggh);

    // --- layer 2 ---
    gemm_n10v2<<<N_NODES / 4, 256, 0, stream>>>(aggh, W2, al2, ar2, feat2, el, er);
    attn2_agg2<<<N_NODES / 4, 256, 0, stream>>>(rp, srcs, perm, el, er, feat2, b2, out);
}

// Round 8
// 581.796 us; speedup vs baseline: 1.5181x; 1.5181x over previous
//
#include <hip/hip_runtime.h>
#include <hip/hip_bf16.h>
#include <hip/hip_fp16.h>

#define N_NODES 50000
#define N_EDGES 500000
#define HEADS 8
#define HID 64
#define HD 512   // HEADS*HID
#define NCLS 10
#define M_PAD 50048  // 391*128, GEMM M padded to tile

typedef _Float16 f16x8 __attribute__((ext_vector_type(8)));
typedef _Float16 h8v   __attribute__((ext_vector_type(8)));
typedef float    f32x4 __attribute__((ext_vector_type(4)));

#define GLD_LDS16(g, l) __builtin_amdgcn_global_load_lds( \
    (__attribute__((address_space(1))) void*)(g),         \
    (__attribute__((address_space(3))) void*)(l), 16, 0, 0)

// ---------------------------------------------------------------------------
// fc projection, both node types in one launch: tiled fp32 GEMM 64x64, BK=16
// ---------------------------------------------------------------------------
#define T0_TILES 469  // ceil(30000/64)
#define T1_TILES 313  // ceil(20000/64)
__global__ __launch_bounds__(256) void fc_gemm(const float* __restrict__ A0,
                                               const float* __restrict__ B0,
                                               const float* __restrict__ bias0,
                                               const float* __restrict__ A1,
                                               const float* __restrict__ B1,
                                               const float* __restrict__ bias1,
                                               _Float16* __restrict__ Cb) {
    __shared__ float As[16][68];
    __shared__ float Bs[16][68];
    int bid = blockIdx.x;
    const float* A; const float* B; const float* bias;
    int M, K, row_off, m0;
    if (bid < T0_TILES) { A = A0; B = B0; bias = bias0; M = 30000; K = 256; row_off = 0;     m0 = bid * 64; }
    else                { A = A1; B = B1; bias = bias1; M = 20000; K = 128; row_off = 30000; m0 = (bid - T0_TILES) * 64; }
    int tid = threadIdx.x;
    int tx = tid & 15, ty = tid >> 4;
    float acc[4][4] = {};
    int arow = tid >> 2;
    int akq  = (tid & 3) * 4;
    int brow = tid >> 4;
    int bcol = (tid & 15) * 4;
    for (int k0 = 0; k0 < K; k0 += 16) {
        int m = m0 + arow;
        float4 av = make_float4(0.f, 0.f, 0.f, 0.f);
        if (m < M) av = *(const float4*)(A + (size_t)m * K + k0 + akq);
        As[akq + 0][arow] = av.x; As[akq + 1][arow] = av.y;
        As[akq + 2][arow] = av.z; As[akq + 3][arow] = av.w;
        float4 bv = *(const float4*)(B + (size_t)(k0 + brow) * 64 + bcol);
        *(float4*)(&Bs[brow][bcol]) = bv;
        __syncthreads();
#pragma unroll
        for (int k = 0; k < 16; k++) {
            float4 a = *(const float4*)(&As[k][ty * 4]);
            float4 b = *(const float4*)(&Bs[k][tx * 4]);
            float av4[4] = {a.x, a.y, a.z, a.w};
            float bv4[4] = {b.x, b.y, b.z, b.w};
#pragma unroll
            for (int i = 0; i < 4; i++)
#pragma unroll
                for (int j = 0; j < 4; j++) acc[i][j] += av4[i] * bv4[j];
        }
        __syncthreads();
    }
#pragma unroll
    for (int i = 0; i < 4; i++) {
        int m = m0 + ty * 4 + i;
        if (m < M) {
#pragma unroll
            for (int j = 0; j < 4; j++) {
                int col = tx * 4 + j;
                Cb[(size_t)(row_off + m) * 64 + col] = (_Float16)(acc[i][j] + bias[col]);
            }
        }
    }
}

// ---------------------------------------------------------------------------
// CSR build: count -> parallel scan (3 kernels) -> scatter
// ---------------------------------------------------------------------------
#define NBLK_SCAN 196  // ceil(50000/256)

__global__ void count_kernel(const int* __restrict__ dst, int* __restrict__ cnt) {
    int t = blockIdx.x * blockDim.x + threadIdx.x;
    if (t < N_EDGES) atomicAdd(&cnt[dst[t]], 1);
}

__global__ void scan_part(const int* __restrict__ cnt, int* __restrict__ part) {
    __shared__ int s[256];
    int i = blockIdx.x * 256 + threadIdx.x;
    s[threadIdx.x] = (i < N_NODES) ? cnt[i] : 0;
    __syncthreads();
    for (int off = 128; off; off >>= 1) {
        if (threadIdx.x < off) s[threadIdx.x] += s[threadIdx.x + off];
        __syncthreads();
    }
    if (threadIdx.x == 0) part[blockIdx.x] = s[0];
}

__global__ void scan_offs(int* __restrict__ part) {
    __shared__ int s[256];
    int tid = threadIdx.x;
    int v = (tid < NBLK_SCAN) ? part[tid] : 0;
    s[tid] = v;
    __syncthreads();
    for (int off = 1; off < 256; off <<= 1) {
        int x = (tid >= off) ? s[tid - off] : 0;
        __syncthreads();
        s[tid] += x;
        __syncthreads();
    }
    if (tid < NBLK_SCAN) part[tid] = s[tid] - v;  // exclusive
}

__global__ void scan_apply(const int* __restrict__ cnt, const int* __restrict__ part,
                           int* __restrict__ rp, int* __restrict__ cur) {
    __shared__ int s[256];
    int tid = threadIdx.x;
    int i = blockIdx.x * 256 + tid;
    int v = (i < N_NODES) ? cnt[i] : 0;
    s[tid] = v;
    __syncthreads();
    for (int off = 1; off < 256; off <<= 1) {
        int x = (tid >= off) ? s[tid - off] : 0;
        __syncthreads();
        s[tid] += x;
        __syncthreads();
    }
    if (i < N_NODES) {
        int excl = s[tid] - v + part[blockIdx.x];
        rp[i] = excl; cur[i] = excl;
    }
    if (i == 0) rp[N_NODES] = N_EDGES;
}

__global__ void scatter_kernel(const int* __restrict__ src, const int* __restrict__ dst,
                               int* __restrict__ cursor, int* __restrict__ src_sorted) {
    int t = blockIdx.x * blockDim.x + threadIdx.x;
    if (t >= N_EDGES) return;
    int pos = atomicAdd(&cursor[dst[t]], 1);
    src_sorted[pos] = src[t];
}

// ---------------------------------------------------------------------------
// weight transpose+cast (both weights, one launch): Wt[n][k] = f16(W[k][n])
// ---------------------------------------------------------------------------
__global__ void wtrans(const float* __restrict__ W0, const float* __restrict__ W1,
                       _Float16* __restrict__ W0t, _Float16* __restrict__ W1t) {
    int t = blockIdx.x * blockDim.x + threadIdx.x;
    if (t < 64 * 512) {
        int n = t >> 6, k = t & 63;
        W0t[t] = (_Float16)W0[k * 512 + n];
    } else {
        int u = t - 64 * 512;
        if (u >= 512 * 512) return;
        int n = u >> 9, k = u & 511;
        W1t[u] = (_Float16)W1[k * 512 + n];
    }
}

// ---------------------------------------------------------------------------
// f16 MFMA GEMM (R4-proven shape): 128x128 tile, BK=32, XOR-4 kgroup swizzle.
// Fused epilogue: el/er per (row, head); each wave's 64 cols = 1 head.
// ---------------------------------------------------------------------------
__global__ __launch_bounds__(256) void gemm_mfma(const _Float16* __restrict__ A,
                                                 const _Float16* __restrict__ Bt,
                                                 _Float16* __restrict__ Cb,
                                                 const float* __restrict__ al,
                                                 const float* __restrict__ ar,
                                                 float* __restrict__ el,
                                                 float* __restrict__ er,
                                                 int M, int N, int K) {
    __shared__ _Float16 Asl[128 * 32];
    __shared__ _Float16 Bsl[128 * 32];
    int t = threadIdx.x;
    int m0 = blockIdx.y * 128, n0 = blockIdx.x * 128;
    int lane = t & 63;
    int w = t >> 6;
    int wm = (w & 1) * 64, wn = (w >> 1) * 64;
    int l15 = lane & 15, quad = lane >> 4;
    f32x4 acc[4][4];
#pragma unroll
    for (int i = 0; i < 4; i++)
#pragma unroll
        for (int j = 0; j < 4; j++) acc[i][j] = (f32x4){0.f, 0.f, 0.f, 0.f};

    int fb0 = t * 16;
    int fb1 = fb0 + 4096;
    int row0 = fb0 >> 6, kg0 = ((fb0 >> 4) & 3) ^ (row0 & 3);
    int row1 = fb1 >> 6, kg1 = ((fb1 >> 4) & 3) ^ (row1 & 3);

    for (int k0 = 0; k0 < K; k0 += 32) {
        GLD_LDS16(A + (size_t)(m0 + row0) * K + k0 + kg0 * 8, (char*)Asl + fb0);
        GLD_LDS16(A + (size_t)(m0 + row1) * K + k0 + kg1 * 8, (char*)Asl + fb1);
        GLD_LDS16(Bt + (size_t)(n0 + row0) * K + k0 + kg0 * 8, (char*)Bsl + fb0);
        GLD_LDS16(Bt + (size_t)(n0 + row1) * K + k0 + kg1 * 8, (char*)Bsl + fb1);
        __syncthreads();
        f16x8 af[4], bfr[4];
#pragma unroll
        for (int i = 0; i < 4; i++) {
            int r = wm + i * 16 + l15;
            int kg = quad ^ (r & 3);
            af[i] = *(const f16x8*)(Asl + r * 32 + kg * 8);
        }
#pragma unroll
        for (int j = 0; j < 4; j++) {
            int r = wn + j * 16 + l15;
            int kg = quad ^ (r & 3);
            bfr[j] = *(const f16x8*)(Bsl + r * 32 + kg * 8);
        }
#pragma unroll
        for (int i = 0; i < 4; i++)
#pragma unroll
            for (int j = 0; j < 4; j++)
                acc[i][j] = __builtin_amdgcn_mfma_f32_16x16x32_f16(af[i], bfr[j], acc[i][j], 0, 0, 0);
        __syncthreads();
    }
#pragma unroll
    for (int i = 0; i < 4; i++) {
        int rbase = m0 + wm + i * 16 + quad * 4;
#pragma unroll
        for (int j = 0; j < 4; j++) {
            int col = n0 + wn + j * 16 + l15;
#pragma unroll
            for (int r = 0; r < 4; r++) {
                int row = rbase + r;
                if (row < M) Cb[(size_t)row * N + col] = (_Float16)acc[i][j][r];
            }
        }
    }
    int h = (n0 + wn) >> 6;
    float alv[4], arv[4];
#pragma unroll
    for (int j = 0; j < 4; j++) {
        alv[j] = al[h * 64 + j * 16 + l15];
        arv[j] = ar[h * 64 + j * 16 + l15];
    }
#pragma unroll
    for (int i = 0; i < 4; i++) {
#pragma unroll
        for (int r = 0; r < 4; r++) {
            float sl = 0.f, sr = 0.f;
#pragma unroll
            for (int j = 0; j < 4; j++) {
                float v = acc[i][j][r];
                sl += v * alv[j]; sr += v * arv[j];
            }
#pragma unroll
            for (int mk = 1; mk < 16; mk <<= 1) {
                sl += __shfl_xor(sl, mk);
                sr += __shfl_xor(sr, mk);
            }
            int row = m0 + wm + i * 16 + quad * 4 + r;
            if (l15 == 0 && row < M) {
                el[row * HEADS + h] = sl;
                er[row * HEADS + h] = sr;
            }
        }
    }
}

// ---------------------------------------------------------------------------
// Shared softmax phase (all 8 heads) for a wave's node n.
// Writes pre-scaled alpha (fast path) or inv/m (slow path) into aS[w].
// ---------------------------------------------------------------------------
__device__ __forceinline__ bool attn_softmax_phase(
        int lane, int w, int n, int s0, int s1,
        const int* __restrict__ srcs, const float* __restrict__ el,
        const float* __restrict__ er,
        float (*aS)[592], int (*sS)[64], float* er8) {
    int deg = s1 - s0;
    {
        f32x4 a = *(const f32x4*)(er + (size_t)n * 8);
        f32x4 b = *(const f32x4*)(er + (size_t)n * 8 + 4);
        er8[0]=a[0]; er8[1]=a[1]; er8[2]=a[2]; er8[3]=a[3];
        er8[4]=b[0]; er8[5]=b[1]; er8[6]=b[2]; er8[7]=b[3];
    }
    bool fast = (deg <= 64);
    if (fast) {
        bool act = lane < deg;
        int sp = act ? srcs[s0 + lane] : 0;
        sS[w][lane] = sp;
        f32x4 ea = {0.f,0.f,0.f,0.f}, eb = {0.f,0.f,0.f,0.f};
        if (act) {
            ea = *(const f32x4*)(el + (size_t)sp * 8);
            eb = *(const f32x4*)(el + (size_t)sp * 8 + 4);
        }
        float e8[8] = {ea[0],ea[1],ea[2],ea[3],eb[0],eb[1],eb[2],eb[3]};
#pragma unroll
        for (int h = 0; h < 8; h++) {
            float e = e8[h] + er8[h];
            e = e > 0.f ? e : 0.2f * e;
            e8[h] = act ? e : -1e30f;
        }
#pragma unroll
        for (int h = 0; h < 8; h++) {
            float mm = e8[h];
#pragma unroll
            for (int mk = 1; mk < 64; mk <<= 1) mm = fmaxf(mm, __shfl_xor(mm, mk));
            float pv = act ? __expf(e8[h] - mm) : 0.f;
            float ss = pv;
#pragma unroll
            for (int mk = 1; mk < 64; mk <<= 1) ss += __shfl_xor(ss, mk);
            aS[w][lane * 9 + h] = pv * (1.f / fmaxf(ss, 1e-9f));  // pre-scaled alpha
        }
    } else {
        float m8[8], s8[8];
#pragma unroll
        for (int h = 0; h < 8; h++) { m8[h] = -1e30f; s8[h] = 0.f; }
        for (int base = s0; base < s1; base += 64) {
            bool act = base + lane < s1;
            int sp = act ? srcs[base + lane] : 0;
            f32x4 ea = {0.f,0.f,0.f,0.f}, eb = {0.f,0.f,0.f,0.f};
            if (act) {
                ea = *(const f32x4*)(el + (size_t)sp * 8);
                eb = *(const f32x4*)(el + (size_t)sp * 8 + 4);
            }
            float ev[8] = {ea[0],ea[1],ea[2],ea[3],eb[0],eb[1],eb[2],eb[3]};
#pragma unroll
            for (int h = 0; h < 8; h++) {
                float e = ev[h] + er8[h];
                e = e > 0.f ? e : 0.2f * e;
                e = act ? e : -1e30f;
                float cm = e;
#pragma unroll
                for (int mk = 1; mk < 64; mk <<= 1) cm = fmaxf(cm, __shfl_xor(cm, mk));
                float nm = fmaxf(m8[h], cm);
                float pv = act ? __expf(e - nm) : 0.f;
#pragma unroll
                for (int mk = 1; mk < 64; mk <<= 1) pv += __shfl_xor(pv, mk);
                s8[h] = s8[h] * __expf(m8[h] - nm) + pv;
                m8[h] = nm;
            }
        }
        if (lane == 0) {
#pragma unroll
            for (int h = 0; h < 8; h++) {
                aS[w][576 + h] = 1.f / fmaxf(s8[h], 1e-9f);
                aS[w][584 + h] = m8[h];
            }
        }
    }
    return fast;
}

// ---------------------------------------------------------------------------
// Phase B: gather+weighted-accumulate; returns x8 (post-elu+bias) per lane.
// lane covers dims [lane*8, lane*8+8); 2-edge ILP in fast path.
// ---------------------------------------------------------------------------
__device__ __forceinline__ void attn_gather_phase(
        int lane, int w, int n, int s0, int s1, bool fast,
        const int* __restrict__ srcs, const float* __restrict__ el,
        const float* __restrict__ er, const _Float16* __restrict__ feat,
        const float* __restrict__ bias,
        float (*aS)[592], int (*sS)[64], float* x8) {
    int deg = s1 - s0;
    int hh = lane >> 3, d0 = (lane & 7) * 8;
    const _Float16* colbase = feat + hh * 64 + d0;
    h8v acc8a = {(_Float16)0, (_Float16)0, (_Float16)0, (_Float16)0,
                 (_Float16)0, (_Float16)0, (_Float16)0, (_Float16)0};
    h8v acc8b = acc8a;
    if (fast) {
        int p = 0;
        for (; p + 2 <= deg; p += 2) {
            int spa = sS[w][p], spb = sS[w][p + 1];
            _Float16 aa = (_Float16)aS[w][p * 9 + hh];
            _Float16 ab = (_Float16)aS[w][(p + 1) * 9 + hh];
            h8v a8a = {aa, aa, aa, aa, aa, aa, aa, aa};
            h8v a8b = {ab, ab, ab, ab, ab, ab, ab, ab};
            h8v fa = *(const h8v*)(colbase + (size_t)spa * HD);
            h8v fb = *(const h8v*)(colbase + (size_t)spb * HD);
            acc8a += a8a * fa;
            acc8b += a8b * fb;
        }
        if (p < deg) {
            int sp = sS[w][p];
            _Float16 ah = (_Float16)aS[w][p * 9 + hh];
            h8v a8 = {ah, ah, ah, ah, ah, ah, ah, ah};
            h8v f = *(const h8v*)(colbase + (size_t)sp * HD);
            acc8a += a8 * f;
        }
    } else {
        float inv_l = aS[w][576 + hh];
        float m_l   = aS[w][584 + hh];
        float ern_l = er[(size_t)n * 8 + hh];
        for (int p = s0; p < s1; p++) {
            int sp = srcs[p];
            float e = el[(size_t)sp * 8 + hh] + ern_l;
            e = e > 0.f ? e : 0.2f * e;
            _Float16 ah = (_Float16)(__expf(e - m_l) * inv_l);
            h8v a8 = {ah, ah, ah, ah, ah, ah, ah, ah};
            h8v f = *(const h8v*)(colbase + (size_t)sp * HD);
            acc8a += a8 * f;
        }
    }
    acc8a += acc8b;
    float4 b0v = *(const float4*)(bias + lane * 8);
    float4 b1v = *(const float4*)(bias + lane * 8 + 4);
    float bb[8] = {b0v.x,b0v.y,b0v.z,b0v.w,b1v.x,b1v.y,b1v.z,b1v.w};
#pragma unroll
    for (int j = 0; j < 8; j++) {
        float x = (float)acc8a[j] + bb[j];
        x8[j] = x > 0.f ? x : __expf(x) - 1.f;
    }
}

// ---------------------------------------------------------------------------
// Layer-0 fused softmax+aggregation: writes f16 row to out.
// ---------------------------------------------------------------------------
__global__ __launch_bounds__(256) void attn_agg(
        const int* __restrict__ rp, const int* __restrict__ srcs,
        const float* __restrict__ el, const float* __restrict__ er,
        const _Float16* __restrict__ feat, const float* __restrict__ bias,
        _Float16* __restrict__ out) {
    __shared__ float aS[4][592];
    __shared__ int   sS[4][64];
    int lane = threadIdx.x & 63;
    int w    = threadIdx.x >> 6;
    int n    = blockIdx.x * 4 + w;
    int s0 = rp[n], s1 = rp[n + 1];
    float er8[8], x8[8];
    bool fast = attn_softmax_phase(lane, w, n, s0, s1, srcs, el, er, aS, sS, er8);
    __syncthreads();
    attn_gather_phase(lane, w, n, s0, s1, fast, srcs, el, er, feat, bias, aS, sS, x8);
    h8v o;
#pragma unroll
    for (int j = 0; j < 8; j++) o[j] = (_Float16)x8[j];
    *(h8v*)(out + (size_t)n * HD + lane * 8) = o;
}

// ---------------------------------------------------------------------------
// Layer-1 fused softmax+aggregation + W2 GEMM + el2/er2 epilogue.
// No 512-dim row is written; feat2[n][10], el2[n], er2[n] only.
// ---------------------------------------------------------------------------
__global__ __launch_bounds__(256) void attn_agg_l1(
        const int* __restrict__ rp, const int* __restrict__ srcs,
        const float* __restrict__ el, const float* __restrict__ er,
        const _Float16* __restrict__ feat, const float* __restrict__ bias,
        const float* __restrict__ W2, const float* __restrict__ al2,
        const float* __restrict__ ar2,
        float* __restrict__ feat2, float* __restrict__ el2,
        float* __restrict__ er2) {
    __shared__ float aS[4][592];
    __shared__ int   sS[4][64];
    __shared__ float W2s[512 * 11];   // [d*11+c]
    int tid = threadIdx.x;
    for (int i = tid; i < 512 * NCLS; i += 256) {
        int d = i / NCLS, c = i - d * NCLS;
        W2s[d * 11 + c] = W2[i];
    }
    int lane = tid & 63;
    int w    = tid >> 6;
    int n    = blockIdx.x * 4 + w;
    int s0 = rp[n], s1 = rp[n + 1];
    float er8[8], x8[8];
    bool fast = attn_softmax_phase(lane, w, n, s0, s1, srcs, el, er, aS, sS, er8);
    __syncthreads();   // covers both aS and W2s
    attn_gather_phase(lane, w, n, s0, s1, fast, srcs, el, er, feat, bias, aS, sS, x8);
    // W2 epilogue: lane covers dims lane*8..lane*8+7
    float partial[NCLS];
#pragma unroll
    for (int c = 0; c < NCLS; c++) partial[c] = 0.f;
    int dbase = lane * 8;
#pragma unroll
    for (int j = 0; j < 8; j++) {
        const float* wr = W2s + (dbase + j) * 11;
        float xv = x8[j];
#pragma unroll
        for (int c = 0; c < NCLS; c++) partial[c] += xv * wr[c];
    }
#pragma unroll
    for (int mk = 1; mk < 64; mk <<= 1)
#pragma unroll
        for (int c = 0; c < NCLS; c++) partial[c] += __shfl_xor(partial[c], mk);
    if (lane == 0) {
        float e1 = 0.f, e2v = 0.f;
#pragma unroll
        for (int c = 0; c < NCLS; c++) {
            feat2[(size_t)n * NCLS + c] = partial[c];
            e1  += partial[c] * al2[c];
            e2v += partial[c] * ar2[c];
        }
        el2[n] = e1; er2[n] = e2v;
    }
}

// ---------------------------------------------------------------------------
// layer 2 fused softmax+aggregation (H=1, D=10), wave per dst node
// ---------------------------------------------------------------------------
__global__ __launch_bounds__(256) void attn2_agg2(
        const int* __restrict__ rp, const int* __restrict__ srcs,
        const float* __restrict__ el, const float* __restrict__ er,
        const float* __restrict__ feat2, const float* __restrict__ b2,
        float* __restrict__ out) {
    int lane = threadIdx.x & 63;
    int n = blockIdx.x * 4 + (threadIdx.x >> 6);
    int s0 = rp[n], s1 = rp[n + 1], deg = s1 - s0;
    float ern = er[n];
    float facc[NCLS];
#pragma unroll
    for (int c = 0; c < NCLS; c++) facc[c] = 0.f;
    if (deg <= 64) {
        bool act = lane < deg;
        int sp = act ? srcs[s0 + lane] : 0;
        float e = act ? el[sp] + ern : 0.f;
        e = e > 0.f ? e : 0.2f * e;
        if (!act) e = -1e30f;
        float mm = e;
#pragma unroll
        for (int mk = 1; mk < 64; mk <<= 1) mm = fmaxf(mm, __shfl_xor(mm, mk));
        float pv = act ? __expf(e - mm) : 0.f;
        float ss = pv;
#pragma unroll
        for (int mk = 1; mk < 64; mk <<= 1) ss += __shfl_xor(ss, mk);
        float a = pv / fmaxf(ss, 1e-9f);
        if (act) {
#pragma unroll
            for (int c = 0; c < NCLS; c++) facc[c] = a * feat2[(size_t)sp * NCLS + c];
        }
    } else {
        float mm = -1e30f, ssum = 0.f;
        for (int base = s0; base < s1; base += 64) {
            bool act = base + lane < s1;
            int sp = act ? srcs[base + lane] : 0;
            float e = act ? el[sp] + ern : 0.f;
            e = e > 0.f ? e : 0.2f * e;
            if (!act) e = -1e30f;
            float cm = e;
#pragma unroll
            for (int mk = 1; mk < 64; mk <<= 1) cm = fmaxf(cm, __shfl_xor(cm, mk));
            float nm = fmaxf(mm, cm);
            float pv = act ? __expf(e - nm) : 0.f;
#pragma unroll
            for (int mk = 1; mk < 64; mk <<= 1) pv += __shfl_xor(pv, mk);
            ssum = ssum * __expf(mm - nm) + pv;
            mm = nm;
        }
        float inv = 1.f / fmaxf(ssum, 1e-9f);
        for (int base = s0; base < s1; base += 64) {
            bool act = base + lane < s1;
            int sp = act ? srcs[base + lane] : 0;
            float e = act ? el[sp] + ern : 0.f;
            e = e > 0.f ? e : 0.2f * e;
            float a = act ? __expf(e - mm) * inv : 0.f;
            if (act) {
#pragma unroll
                for (int c = 0; c < NCLS; c++) facc[c] += a * feat2[(size_t)sp * NCLS + c];
            }
        }
    }
#pragma unroll
    for (int c = 0; c < NCLS; c++)
#pragma unroll
        for (int mk = 1; mk < 64; mk <<= 1) facc[c] += __shfl_xor(facc[c], mk);
    if (lane == 0) {
#pragma unroll
        for (int c = 0; c < NCLS; c++) out[(size_t)n * NCLS + c] = facc[c] + b2[c];
    }
}

// ---------------------------------------------------------------------------
extern "C" void kernel_launch(void* const* d_in, const int* in_sizes, int n_in,
                              void* d_out, int out_size, void* d_ws, size_t ws_size,
                              hipStream_t stream) {
    const float* feat0 = (const float*)d_in[0];
    const float* feat1 = (const float*)d_in[1];
    const float* fc0_w = (const float*)d_in[2];
    const float* fc0_b = (const float*)d_in[3];
    const float* fc1_w = (const float*)d_in[4];
    const float* fc1_b = (const float*)d_in[5];
    const float* W0    = (const float*)d_in[6];
    const float* al0   = (const float*)d_in[7];
    const float* ar0   = (const float*)d_in[8];
    const float* b0    = (const float*)d_in[9];
    const float* W1    = (const float*)d_in[10];
    const float* al1   = (const float*)d_in[11];
    const float* ar1   = (const float*)d_in[12];
    const float* b1    = (const float*)d_in[13];
    const float* W2    = (const float*)d_in[14];
    const float* al2   = (const float*)d_in[15];
    const float* ar2   = (const float*)d_in[16];
    const float* b2    = (const float*)d_in[17];
    const int* eidx    = (const int*)d_in[18];
    const int* src = eidx;
    const int* dst = eidx + N_EDGES;
    float* out = (float*)d_out;

    char* ws = (char*)d_ws;
    size_t off = 0;
    auto alloc = [&](size_t bytes) { size_t o = off; off = (off + bytes + 255) & ~(size_t)255; return o; };

    _Float16* featA = (_Float16*)(ws + alloc((size_t)M_PAD * HD * 2));
    _Float16* aggh  = (_Float16*)(ws + alloc((size_t)M_PAD * HD * 2));
    _Float16* h0h   = (_Float16*)(ws + alloc((size_t)M_PAD * 64 * 2));
    float*    feat2 = (float*)(ws + alloc((size_t)N_NODES * NCLS * 4));
    float*    el    = (float*)(ws + alloc((size_t)N_NODES * HEADS * 4));
    float*    er    = (float*)(ws + alloc((size_t)N_NODES * HEADS * 4));
    float*    el2   = (float*)(ws + alloc((size_t)N_NODES * 4));
    float*    er2   = (float*)(ws + alloc((size_t)N_NODES * 4));
    int*      cnt   = (int*)  (ws + alloc((size_t)N_NODES * 4));
    int*      rp    = (int*)  (ws + alloc((size_t)(N_NODES + 1) * 4));
    int*      cur   = (int*)  (ws + alloc((size_t)N_NODES * 4));
    int*      srcs  = (int*)  (ws + alloc((size_t)N_EDGES * 4));
    int*      part  = (int*)  (ws + alloc(1024));
    _Float16* W0t   = (_Float16*)(ws + alloc(512 * 64 * 2));
    _Float16* W1t   = (_Float16*)(ws + alloc(512 * 512 * 2));

    // --- fc projection (both types, one launch) ---
    fc_gemm<<<T0_TILES + T1_TILES, 256, 0, stream>>>(feat0, fc0_w, fc0_b,
                                                     feat1, fc1_w, fc1_b, h0h);
    // --- weight transpose+cast (one launch) ---
    wtrans<<<(64 * 512 + 512 * 512 + 255) / 256, 256, 0, stream>>>(W0, W1, W0t, W1t);

    // --- CSR build ---
    hipMemsetAsync(cnt, 0, N_NODES * sizeof(int), stream);
    count_kernel<<<(N_EDGES + 255) / 256, 256, 0, stream>>>(dst, cnt);
    scan_part<<<NBLK_SCAN, 256, 0, stream>>>(cnt, part);
    scan_offs<<<1, 256, 0, stream>>>(part);
    scan_apply<<<NBLK_SCAN, 256, 0, stream>>>(cnt, part, rp, cur);
    scatter_kernel<<<(N_EDGES + 255) / 256, 256, 0, stream>>>(src, dst, cur, srcs);

    dim3 ggrid(HD / 128, M_PAD / 128);  // (4, 391)

    // --- layer 0 ---
    gemm_mfma<<<ggrid, 256, 0, stream>>>(h0h, W0t, featA, al0, ar0, el, er,
                                         N_NODES, HD, 64);
    attn_agg<<<N_NODES / 4, 256, 0, stream>>>(rp, srcs, el, er, featA, b0, aggh);

    // --- layer 1 (attn fused with W2 GEMM + el2/er2) ---
    gemm_mfma<<<ggrid, 256, 0, stream>>>(aggh, W1t, featA, al1, ar1, el, er,
                                         N_NODES, HD, HD);
    attn_agg_l1<<<N_NODES / 4, 256, 0, stream>>>(rp, srcs, el, er, featA, b1,
                                                 W2, al2, ar2, feat2, el2, er2);

    // --- layer 2 ---
    attn2_agg2<<<N_NODES / 4, 256, 0, stream>>>(rp, srcs, el2, er2, feat2, b2, out);
}

// Round 9
// 544.282 us; speedup vs baseline: 1.6228x; 1.0689x over previous
//
#include <hip/hip_runtime.h>
#include <hip/hip_bf16.h>
#include <hip/hip_fp16.h>

#define N_NODES 50000
#define N_EDGES 500000
#define HEADS 8
#define HID 64
#define HD 512   // HEADS*HID
#define NCLS 10
#define M_PAD 50048  // 391*128, GEMM M padded to tile

typedef _Float16 f16x8 __attribute__((ext_vector_type(8)));
typedef _Float16 h8v   __attribute__((ext_vector_type(8)));
typedef float    f32x4 __attribute__((ext_vector_type(4)));

#define GLD_LDS16(g, l) __builtin_amdgcn_global_load_lds( \
    (__attribute__((address_space(1))) void*)(g),         \
    (__attribute__((address_space(3))) void*)(l), 16, 0, 0)

// ---------------------------------------------------------------------------
// fc projection, both node types in one launch: tiled fp32 GEMM 64x64, BK=16
// ---------------------------------------------------------------------------
#define T0_TILES 469  // ceil(30000/64)
#define T1_TILES 313  // ceil(20000/64)
__global__ __launch_bounds__(256) void fc_gemm(const float* __restrict__ A0,
                                               const float* __restrict__ B0,
                                               const float* __restrict__ bias0,
                                               const float* __restrict__ A1,
                                               const float* __restrict__ B1,
                                               const float* __restrict__ bias1,
                                               _Float16* __restrict__ Cb) {
    __shared__ float As[16][68];
    __shared__ float Bs[16][68];
    int bid = blockIdx.x;
    const float* A; const float* B; const float* bias;
    int M, K, row_off, m0;
    if (bid < T0_TILES) { A = A0; B = B0; bias = bias0; M = 30000; K = 256; row_off = 0;     m0 = bid * 64; }
    else                { A = A1; B = B1; bias = bias1; M = 20000; K = 128; row_off = 30000; m0 = (bid - T0_TILES) * 64; }
    int tid = threadIdx.x;
    int tx = tid & 15, ty = tid >> 4;
    float acc[4][4] = {};
    int arow = tid >> 2;
    int akq  = (tid & 3) * 4;
    int brow = tid >> 4;
    int bcol = (tid & 15) * 4;
    for (int k0 = 0; k0 < K; k0 += 16) {
        int m = m0 + arow;
        float4 av = make_float4(0.f, 0.f, 0.f, 0.f);
        if (m < M) av = *(const float4*)(A + (size_t)m * K + k0 + akq);
        As[akq + 0][arow] = av.x; As[akq + 1][arow] = av.y;
        As[akq + 2][arow] = av.z; As[akq + 3][arow] = av.w;
        float4 bv = *(const float4*)(B + (size_t)(k0 + brow) * 64 + bcol);
        *(float4*)(&Bs[brow][bcol]) = bv;
        __syncthreads();
#pragma unroll
        for (int k = 0; k < 16; k++) {
            float4 a = *(const float4*)(&As[k][ty * 4]);
            float4 b = *(const float4*)(&Bs[k][tx * 4]);
            float av4[4] = {a.x, a.y, a.z, a.w};
            float bv4[4] = {b.x, b.y, b.z, b.w};
#pragma unroll
            for (int i = 0; i < 4; i++)
#pragma unroll
                for (int j = 0; j < 4; j++) acc[i][j] += av4[i] * bv4[j];
        }
        __syncthreads();
    }
#pragma unroll
    for (int i = 0; i < 4; i++) {
        int m = m0 + ty * 4 + i;
        if (m < M) {
#pragma unroll
            for (int j = 0; j < 4; j++) {
                int col = tx * 4 + j;
                Cb[(size_t)(row_off + m) * 64 + col] = (_Float16)(acc[i][j] + bias[col]);
            }
        }
    }
}

// ---------------------------------------------------------------------------
// CSR build: count -> parallel scan (3 kernels) -> scatter
// ---------------------------------------------------------------------------
#define NBLK_SCAN 196  // ceil(50000/256)

__global__ void count_kernel(const int* __restrict__ dst, int* __restrict__ cnt) {
    int t = blockIdx.x * blockDim.x + threadIdx.x;
    if (t < N_EDGES) atomicAdd(&cnt[dst[t]], 1);
}

__global__ void scan_part(const int* __restrict__ cnt, int* __restrict__ part) {
    __shared__ int s[256];
    int i = blockIdx.x * 256 + threadIdx.x;
    s[threadIdx.x] = (i < N_NODES) ? cnt[i] : 0;
    __syncthreads();
    for (int off = 128; off; off >>= 1) {
        if (threadIdx.x < off) s[threadIdx.x] += s[threadIdx.x + off];
        __syncthreads();
    }
    if (threadIdx.x == 0) part[blockIdx.x] = s[0];
}

__global__ void scan_offs(int* __restrict__ part) {
    __shared__ int s[256];
    int tid = threadIdx.x;
    int v = (tid < NBLK_SCAN) ? part[tid] : 0;
    s[tid] = v;
    __syncthreads();
    for (int off = 1; off < 256; off <<= 1) {
        int x = (tid >= off) ? s[tid - off] : 0;
        __syncthreads();
        s[tid] += x;
        __syncthreads();
    }
    if (tid < NBLK_SCAN) part[tid] = s[tid] - v;  // exclusive
}

__global__ void scan_apply(const int* __restrict__ cnt, const int* __restrict__ part,
                           int* __restrict__ rp, int* __restrict__ cur) {
    __shared__ int s[256];
    int tid = threadIdx.x;
    int i = blockIdx.x * 256 + tid;
    int v = (i < N_NODES) ? cnt[i] : 0;
    s[tid] = v;
    __syncthreads();
    for (int off = 1; off < 256; off <<= 1) {
        int x = (tid >= off) ? s[tid - off] : 0;
        __syncthreads();
        s[tid] += x;
        __syncthreads();
    }
    if (i < N_NODES) {
        int excl = s[tid] - v + part[blockIdx.x];
        rp[i] = excl; cur[i] = excl;
    }
    if (i == 0) rp[N_NODES] = N_EDGES;
}

__global__ void scatter_kernel(const int* __restrict__ src, const int* __restrict__ dst,
                               int* __restrict__ cursor, int* __restrict__ src_sorted) {
    int t = blockIdx.x * blockDim.x + threadIdx.x;
    if (t >= N_EDGES) return;
    int pos = atomicAdd(&cursor[dst[t]], 1);
    src_sorted[pos] = src[t];
}

// ---------------------------------------------------------------------------
// weight transpose+cast (both weights, one launch): Wt[n][k] = f16(W[k][n])
// ---------------------------------------------------------------------------
__global__ void wtrans(const float* __restrict__ W0, const float* __restrict__ W1,
                       _Float16* __restrict__ W0t, _Float16* __restrict__ W1t) {
    int t = blockIdx.x * blockDim.x + threadIdx.x;
    if (t < 64 * 512) {
        int n = t >> 6, k = t & 63;
        W0t[t] = (_Float16)W0[k * 512 + n];
    } else {
        int u = t - 64 * 512;
        if (u >= 512 * 512) return;
        int n = u >> 9, k = u & 511;
        W1t[u] = (_Float16)W1[k * 512 + n];
    }
}

// ---------------------------------------------------------------------------
// f16 MFMA GEMM (R4-proven shape): 128x128 tile, BK=32, XOR-4 kgroup swizzle.
// Fused epilogue: el/er per (row, head); each wave's 64 cols = 1 head.
// ---------------------------------------------------------------------------
__global__ __launch_bounds__(256) void gemm_mfma(const _Float16* __restrict__ A,
                                                 const _Float16* __restrict__ Bt,
                                                 _Float16* __restrict__ Cb,
                                                 const float* __restrict__ al,
                                                 const float* __restrict__ ar,
                                                 float* __restrict__ el,
                                                 float* __restrict__ er,
                                                 int M, int N, int K) {
    __shared__ _Float16 Asl[128 * 32];
    __shared__ _Float16 Bsl[128 * 32];
    int t = threadIdx.x;
    int m0 = blockIdx.y * 128, n0 = blockIdx.x * 128;
    int lane = t & 63;
    int w = t >> 6;
    int wm = (w & 1) * 64, wn = (w >> 1) * 64;
    int l15 = lane & 15, quad = lane >> 4;
    f32x4 acc[4][4];
#pragma unroll
    for (int i = 0; i < 4; i++)
#pragma unroll
        for (int j = 0; j < 4; j++) acc[i][j] = (f32x4){0.f, 0.f, 0.f, 0.f};

    int fb0 = t * 16;
    int fb1 = fb0 + 4096;
    int row0 = fb0 >> 6, kg0 = ((fb0 >> 4) & 3) ^ (row0 & 3);
    int row1 = fb1 >> 6, kg1 = ((fb1 >> 4) & 3) ^ (row1 & 3);

    for (int k0 = 0; k0 < K; k0 += 32) {
        GLD_LDS16(A + (size_t)(m0 + row0) * K + k0 + kg0 * 8, (char*)Asl + fb0);
        GLD_LDS16(A + (size_t)(m0 + row1) * K + k0 + kg1 * 8, (char*)Asl + fb1);
        GLD_LDS16(Bt + (size_t)(n0 + row0) * K + k0 + kg0 * 8, (char*)Bsl + fb0);
        GLD_LDS16(Bt + (size_t)(n0 + row1) * K + k0 + kg1 * 8, (char*)Bsl + fb1);
        __syncthreads();
        f16x8 af[4], bfr[4];
#pragma unroll
        for (int i = 0; i < 4; i++) {
            int r = wm + i * 16 + l15;
            int kg = quad ^ (r & 3);
            af[i] = *(const f16x8*)(Asl + r * 32 + kg * 8);
        }
#pragma unroll
        for (int j = 0; j < 4; j++) {
            int r = wn + j * 16 + l15;
            int kg = quad ^ (r & 3);
            bfr[j] = *(const f16x8*)(Bsl + r * 32 + kg * 8);
        }
#pragma unroll
        for (int i = 0; i < 4; i++)
#pragma unroll
            for (int j = 0; j < 4; j++)
                acc[i][j] = __builtin_amdgcn_mfma_f32_16x16x32_f16(af[i], bfr[j], acc[i][j], 0, 0, 0);
        __syncthreads();
    }
#pragma unroll
    for (int i = 0; i < 4; i++) {
        int rbase = m0 + wm + i * 16 + quad * 4;
#pragma unroll
        for (int j = 0; j < 4; j++) {
            int col = n0 + wn + j * 16 + l15;
#pragma unroll
            for (int r = 0; r < 4; r++) {
                int row = rbase + r;
                if (row < M) Cb[(size_t)row * N + col] = (_Float16)acc[i][j][r];
            }
        }
    }
    int h = (n0 + wn) >> 6;
    float alv[4], arv[4];
#pragma unroll
    for (int j = 0; j < 4; j++) {
        alv[j] = al[h * 64 + j * 16 + l15];
        arv[j] = ar[h * 64 + j * 16 + l15];
    }
#pragma unroll
    for (int i = 0; i < 4; i++) {
#pragma unroll
        for (int r = 0; r < 4; r++) {
            float sl = 0.f, sr = 0.f;
#pragma unroll
            for (int j = 0; j < 4; j++) {
                float v = acc[i][j][r];
                sl += v * alv[j]; sr += v * arv[j];
            }
#pragma unroll
            for (int mk = 1; mk < 16; mk <<= 1) {
                sl += __shfl_xor(sl, mk);
                sr += __shfl_xor(sr, mk);
            }
            int row = m0 + wm + i * 16 + quad * 4 + r;
            if (l15 == 0 && row < M) {
                el[row * HEADS + h] = sl;
                er[row * HEADS + h] = sr;
            }
        }
    }
}

// ---------------------------------------------------------------------------
// Fused edge softmax + aggregation, wave per dst node. NO block barrier:
// aS[w]/sS[w] are wave-private (lockstep wave + compiler lgkmcnt ordering).
// Phase A (lanes=edges): softmax all 8 heads, pre-scaled alpha -> LDS.
// Phase B (lanes=dims): one dwordx4 per edge = full 1KB row; packed f16 FMA.
// ---------------------------------------------------------------------------
__global__ __launch_bounds__(256) void attn_agg(
        const int* __restrict__ rp, const int* __restrict__ srcs,
        const float* __restrict__ el, const float* __restrict__ er,
        const _Float16* __restrict__ feat, const float* __restrict__ bias,
        _Float16* __restrict__ out) {
    __shared__ float aS[4][592];   // [0..575] alpha (p*9+h), [576..583] inv, [584..591] m
    __shared__ int   sS[4][64];
    int lane = threadIdx.x & 63;
    int w    = threadIdx.x >> 6;
    int n    = blockIdx.x * 4 + w;
    int s0 = rp[n], s1 = rp[n + 1];
    int deg = s1 - s0;
    float er8[8];
    {
        f32x4 a = *(const f32x4*)(er + (size_t)n * 8);
        f32x4 b = *(const f32x4*)(er + (size_t)n * 8 + 4);
        er8[0]=a[0]; er8[1]=a[1]; er8[2]=a[2]; er8[3]=a[3];
        er8[4]=b[0]; er8[5]=b[1]; er8[6]=b[2]; er8[7]=b[3];
    }
    bool fast = (deg <= 64);
    if (fast) {
        bool act = lane < deg;
        int sp = act ? srcs[s0 + lane] : 0;
        sS[w][lane] = sp;
        f32x4 ea = {0.f,0.f,0.f,0.f}, eb = {0.f,0.f,0.f,0.f};
        if (act) {
            ea = *(const f32x4*)(el + (size_t)sp * 8);
            eb = *(const f32x4*)(el + (size_t)sp * 8 + 4);
        }
        float e8[8] = {ea[0],ea[1],ea[2],ea[3],eb[0],eb[1],eb[2],eb[3]};
#pragma unroll
        for (int h = 0; h < 8; h++) {
            float e = e8[h] + er8[h];
            e = e > 0.f ? e : 0.2f * e;
            e8[h] = act ? e : -1e30f;
        }
#pragma unroll
        for (int h = 0; h < 8; h++) {
            float mm = e8[h];
#pragma unroll
            for (int mk = 1; mk < 64; mk <<= 1) mm = fmaxf(mm, __shfl_xor(mm, mk));
            float pv = act ? __expf(e8[h] - mm) : 0.f;
            float ss = pv;
#pragma unroll
            for (int mk = 1; mk < 64; mk <<= 1) ss += __shfl_xor(ss, mk);
            aS[w][lane * 9 + h] = pv * (1.f / fmaxf(ss, 1e-9f));  // pre-scaled alpha
        }
    } else {
        float m8[8], s8[8];
#pragma unroll
        for (int h = 0; h < 8; h++) { m8[h] = -1e30f; s8[h] = 0.f; }
        for (int base = s0; base < s1; base += 64) {
            bool act = base + lane < s1;
            int sp = act ? srcs[base + lane] : 0;
            f32x4 ea = {0.f,0.f,0.f,0.f}, eb = {0.f,0.f,0.f,0.f};
            if (act) {
                ea = *(const f32x4*)(el + (size_t)sp * 8);
                eb = *(const f32x4*)(el + (size_t)sp * 8 + 4);
            }
            float ev[8] = {ea[0],ea[1],ea[2],ea[3],eb[0],eb[1],eb[2],eb[3]};
#pragma unroll
            for (int h = 0; h < 8; h++) {
                float e = ev[h] + er8[h];
                e = e > 0.f ? e : 0.2f * e;
                e = act ? e : -1e30f;
                float cm = e;
#pragma unroll
                for (int mk = 1; mk < 64; mk <<= 1) cm = fmaxf(cm, __shfl_xor(cm, mk));
                float nm = fmaxf(m8[h], cm);
                float pv = act ? __expf(e - nm) : 0.f;
#pragma unroll
                for (int mk = 1; mk < 64; mk <<= 1) pv += __shfl_xor(pv, mk);
                s8[h] = s8[h] * __expf(m8[h] - nm) + pv;
                m8[h] = nm;
            }
        }
        if (lane == 0) {
#pragma unroll
            for (int h = 0; h < 8; h++) {
                aS[w][576 + h] = 1.f / fmaxf(s8[h], 1e-9f);
                aS[w][584 + h] = m8[h];
            }
        }
    }
    // wave-private LDS handoff: no __syncthreads needed (lockstep wave,
    // compiler inserts s_waitcnt lgkmcnt for the LDS RAW dependency)
    __builtin_amdgcn_wave_barrier();
    int hh = lane >> 3, d0 = (lane & 7) * 8;   // lane*8 = hh*64 + d0
    h8v acc8a = {(_Float16)0, (_Float16)0, (_Float16)0, (_Float16)0,
                 (_Float16)0, (_Float16)0, (_Float16)0, (_Float16)0};
    h8v acc8b = acc8a;
    const _Float16* colbase = feat + hh * 64 + d0;
    if (fast) {
        int p = 0;
        for (; p + 2 <= deg; p += 2) {
            int spa = sS[w][p], spb = sS[w][p + 1];
            _Float16 aa = (_Float16)aS[w][p * 9 + hh];
            _Float16 ab = (_Float16)aS[w][(p + 1) * 9 + hh];
            h8v a8a = {aa, aa, aa, aa, aa, aa, aa, aa};
            h8v a8b = {ab, ab, ab, ab, ab, ab, ab, ab};
            h8v fa = *(const h8v*)(colbase + (size_t)spa * HD);
            h8v fb = *(const h8v*)(colbase + (size_t)spb * HD);
            acc8a += a8a * fa;
            acc8b += a8b * fb;
        }
        if (p < deg) {
            int sp = sS[w][p];
            _Float16 ah = (_Float16)aS[w][p * 9 + hh];
            h8v a8 = {ah, ah, ah, ah, ah, ah, ah, ah};
            h8v f = *(const h8v*)(colbase + (size_t)sp * HD);
            acc8a += a8 * f;
        }
    } else {
        float inv_l = aS[w][576 + hh];
        float m_l   = aS[w][584 + hh];
        float ern_l = er[(size_t)n * 8 + hh];
        for (int p = s0; p < s1; p++) {
            int sp = srcs[p];
            float e = el[(size_t)sp * 8 + hh] + ern_l;
            e = e > 0.f ? e : 0.2f * e;
            _Float16 ah = (_Float16)(__expf(e - m_l) * inv_l);
            h8v a8 = {ah, ah, ah, ah, ah, ah, ah, ah};
            h8v f = *(const h8v*)(colbase + (size_t)sp * HD);
            acc8a += a8 * f;
        }
    }
    acc8a += acc8b;
    float4 b0v = *(const float4*)(bias + lane * 8);
    float4 b1v = *(const float4*)(bias + lane * 8 + 4);
    float bb[8] = {b0v.x,b0v.y,b0v.z,b0v.w,b1v.x,b1v.y,b1v.z,b1v.w};
    h8v o;
#pragma unroll
    for (int j = 0; j < 8; j++) {
        float x = (float)acc8a[j] + bb[j];
        x = x > 0.f ? x : __expf(x) - 1.f;
        o[j] = (_Float16)x;
    }
    *(h8v*)(out + (size_t)n * HD + lane * 8) = o;
}

// ---------------------------------------------------------------------------
// layer 2 GEMM (N=10) from f16 A, fused el2/er2 epilogue
// ---------------------------------------------------------------------------
__global__ __launch_bounds__(256) void gemm_n10v2(
        const _Float16* __restrict__ A, const float* __restrict__ B,
        const float* __restrict__ al2, const float* __restrict__ ar2,
        float* __restrict__ C, float* __restrict__ el, float* __restrict__ er) {
    __shared__ float Bs[512 * 11];
    int t = threadIdx.x;
    for (int i = t; i < 512 * NCLS; i += 256) {
        int k = i / NCLS, c = i - k * NCLS;
        Bs[k * 11 + c] = B[i];
    }
    __syncthreads();
    int lane = t & 63;
    int m = blockIdx.x * 4 + (t >> 6);
    float acc[NCLS];
#pragma unroll
    for (int c = 0; c < NCLS; c++) acc[c] = 0.f;
    const _Float16* a = A + (size_t)m * HD;
#pragma unroll
    for (int j = 0; j < 8; j++) {
        float av = (float)a[j * 64 + lane];
        const float* br = Bs + (j * 64 + lane) * 11;
#pragma unroll
        for (int c = 0; c < NCLS; c++) acc[c] += av * br[c];
    }
#pragma unroll
    for (int c = 0; c < NCLS; c++)
#pragma unroll
        for (int mk = 1; mk < 64; mk <<= 1) acc[c] += __shfl_xor(acc[c], mk);
    if (lane == 0) {
        float e1 = 0.f, e2 = 0.f;
#pragma unroll
        for (int c = 0; c < NCLS; c++) { e1 += acc[c] * al2[c]; e2 += acc[c] * ar2[c]; }
        el[m] = e1; er[m] = e2;
#pragma unroll
        for (int c = 0; c < NCLS; c++) C[(size_t)m * NCLS + c] = acc[c];
    }
}

// ---------------------------------------------------------------------------
// layer 2 fused softmax+aggregation (H=1, D=10), wave per dst node
// ---------------------------------------------------------------------------
__global__ __launch_bounds__(256) void attn2_agg2(
        const int* __restrict__ rp, const int* __restrict__ srcs,
        const float* __restrict__ el, const float* __restrict__ er,
        const float* __restrict__ feat2, const float* __restrict__ b2,
        float* __restrict__ out) {
    int lane = threadIdx.x & 63;
    int n = blockIdx.x * 4 + (threadIdx.x >> 6);
    int s0 = rp[n], s1 = rp[n + 1], deg = s1 - s0;
    float ern = er[n];
    float facc[NCLS];
#pragma unroll
    for (int c = 0; c < NCLS; c++) facc[c] = 0.f;
    if (deg <= 64) {
        bool act = lane < deg;
        int sp = act ? srcs[s0 + lane] : 0;
        float e = act ? el[sp] + ern : 0.f;
        e = e > 0.f ? e : 0.2f * e;
        if (!act) e = -1e30f;
        float mm = e;
#pragma unroll
        for (int mk = 1; mk < 64; mk <<= 1) mm = fmaxf(mm, __shfl_xor(mm, mk));
        float pv = act ? __expf(e - mm) : 0.f;
        float ss = pv;
#pragma unroll
        for (int mk = 1; mk < 64; mk <<= 1) ss += __shfl_xor(ss, mk);
        float a = pv / fmaxf(ss, 1e-9f);
        if (act) {
#pragma unroll
            for (int c = 0; c < NCLS; c++) facc[c] = a * feat2[(size_t)sp * NCLS + c];
        }
    } else {
        float mm = -1e30f, ssum = 0.f;
        for (int base = s0; base < s1; base += 64) {
            bool act = base + lane < s1;
            int sp = act ? srcs[base + lane] : 0;
            float e = act ? el[sp] + ern : 0.f;
            e = e > 0.f ? e : 0.2f * e;
            if (!act) e = -1e30f;
            float cm = e;
#pragma unroll
            for (int mk = 1; mk < 64; mk <<= 1) cm = fmaxf(cm, __shfl_xor(cm, mk));
            float nm = fmaxf(mm, cm);
            float pv = act ? __expf(e - nm) : 0.f;
#pragma unroll
            for (int mk = 1; mk < 64; mk <<= 1) pv += __shfl_xor(pv, mk);
            ssum = ssum * __expf(mm - nm) + pv;
            mm = nm;
        }
        float inv = 1.f / fmaxf(ssum, 1e-9f);
        for (int base = s0; base < s1; base += 64) {
            bool act = base + lane < s1;
            int sp = act ? srcs[base + lane] : 0;
            float e = act ? el[sp] + ern : 0.f;
            e = e > 0.f ? e : 0.2f * e;
            float a = act ? __expf(e - mm) * inv : 0.f;
            if (act) {
#pragma unroll
                for (int c = 0; c < NCLS; c++) facc[c] += a * feat2[(size_t)sp * NCLS + c];
            }
        }
    }
#pragma unroll
    for (int c = 0; c < NCLS; c++)
#pragma unroll
        for (int mk = 1; mk < 64; mk <<= 1) facc[c] += __shfl_xor(facc[c], mk);
    if (lane == 0) {
#pragma unroll
        for (int c = 0; c < NCLS; c++) out[(size_t)n * NCLS + c] = facc[c] + b2[c];
    }
}

// ---------------------------------------------------------------------------
extern "C" void kernel_launch(void* const* d_in, const int* in_sizes, int n_in,
                              void* d_out, int out_size, void* d_ws, size_t ws_size,
                              hipStream_t stream) {
    const float* feat0 = (const float*)d_in[0];
    const float* feat1 = (const float*)d_in[1];
    const float* fc0_w = (const float*)d_in[2];
    const float* fc0_b = (const float*)d_in[3];
    const float* fc1_w = (const float*)d_in[4];
    const float* fc1_b = (const float*)d_in[5];
    const float* W0    = (const float*)d_in[6];
    const float* al0   = (const float*)d_in[7];
    const float* ar0   = (const float*)d_in[8];
    const float* b0    = (const float*)d_in[9];
    const float* W1    = (const float*)d_in[10];
    const float* al1   = (const float*)d_in[11];
    const float* ar1   = (const float*)d_in[12];
    const float* b1    = (const float*)d_in[13];
    const float* W2    = (const float*)d_in[14];
    const float* al2   = (const float*)d_in[15];
    const float* ar2   = (const float*)d_in[16];
    const float* b2    = (const float*)d_in[17];
    const int* eidx    = (const int*)d_in[18];
    const int* src = eidx;
    const int* dst = eidx + N_EDGES;
    float* out = (float*)d_out;

    char* ws = (char*)d_ws;
    size_t off = 0;
    auto alloc = [&](size_t bytes) { size_t o = off; off = (off + bytes + 255) & ~(size_t)255; return o; };

    _Float16* featA = (_Float16*)(ws + alloc((size_t)M_PAD * HD * 2));
    _Float16* aggh  = (_Float16*)(ws + alloc((size_t)M_PAD * HD * 2));
    _Float16* h0h   = (_Float16*)(ws + alloc((size_t)M_PAD * 64 * 2));
    float*    feat2 = (float*)(ws + alloc((size_t)N_NODES * NCLS * 4));
    float*    el    = (float*)(ws + alloc((size_t)N_NODES * HEADS * 4));
    float*    er    = (float*)(ws + alloc((size_t)N_NODES * HEADS * 4));
    float*    el2   = (float*)(ws + alloc((size_t)N_NODES * 4));
    float*    er2   = (float*)(ws + alloc((size_t)N_NODES * 4));
    int*      cnt   = (int*)  (ws + alloc((size_t)N_NODES * 4));
    int*      rp    = (int*)  (ws + alloc((size_t)(N_NODES + 1) * 4));
    int*      cur   = (int*)  (ws + alloc((size_t)N_NODES * 4));
    int*      srcs  = (int*)  (ws + alloc((size_t)N_EDGES * 4));
    int*      part  = (int*)  (ws + alloc(1024));
    _Float16* W0t   = (_Float16*)(ws + alloc(512 * 64 * 2));
    _Float16* W1t   = (_Float16*)(ws + alloc(512 * 512 * 2));

    // --- fc projection (both types, one launch) ---
    fc_gemm<<<T0_TILES + T1_TILES, 256, 0, stream>>>(feat0, fc0_w, fc0_b,
                                                     feat1, fc1_w, fc1_b, h0h);
    // --- weight transpose+cast (one launch) ---
    wtrans<<<(64 * 512 + 512 * 512 + 255) / 256, 256, 0, stream>>>(W0, W1, W0t, W1t);

    // --- CSR build ---
    hipMemsetAsync(cnt, 0, N_NODES * sizeof(int), stream);
    count_kernel<<<(N_EDGES + 255) / 256, 256, 0, stream>>>(dst, cnt);
    scan_part<<<NBLK_SCAN, 256, 0, stream>>>(cnt, part);
    scan_offs<<<1, 256, 0, stream>>>(part);
    scan_apply<<<NBLK_SCAN, 256, 0, stream>>>(cnt, part, rp, cur);
    scatter_kernel<<<(N_EDGES + 255) / 256, 256, 0, stream>>>(src, dst, cur, srcs);

    dim3 ggrid(HD / 128, M_PAD / 128);  // (4, 391)

    // --- layer 0 ---
    gemm_mfma<<<ggrid, 256, 0, stream>>>(h0h, W0t, featA, al0, ar0, el, er,
                                         N_NODES, HD, 64);
    attn_agg<<<N_NODES / 4, 256, 0, stream>>>(rp, srcs, el, er, featA, b0, aggh);

    // --- layer 1 ---
    gemm_mfma<<<ggrid, 256, 0, stream>>>(aggh, W1t, featA, al1, ar1, el, er,
                                         N_NODES, HD, HD);
    attn_agg<<<N_NODES / 4, 256, 0, stream>>>(rp, srcs, el, er, featA, b1, aggh);

    // --- layer 2 ---
    gemm_n10v2<<<N_NODES / 4, 256, 0, stream>>>(aggh, W2, al2, ar2, feat2, el2, er2);
    attn2_agg2<<<N_NODES / 4, 256, 0, stream>>>(rp, srcs, el2, er2, feat2, b2, out);
}

// Round 10
// 535.764 us; speedup vs baseline: 1.6486x; 1.0159x over previous
//
#include <hip/hip_runtime.h>
#include <hip/hip_bf16.h>
#include <hip/hip_fp16.h>

#define N_NODES 50000
#define N_EDGES 500000
#define HEADS 8
#define HID 64
#define HD 512   // HEADS*HID
#define NCLS 10
#define M_PAD 50048  // 391*128
#define YTILES 391

typedef _Float16 f16x8 __attribute__((ext_vector_type(8)));
typedef _Float16 h8v   __attribute__((ext_vector_type(8)));
typedef float    f32x4 __attribute__((ext_vector_type(4)));

#define GLD_LDS16(g, l) __builtin_amdgcn_global_load_lds( \
    (__attribute__((address_space(1))) void*)(g),         \
    (__attribute__((address_space(3))) void*)(l), 16, 0, 0)

// ---------------------------------------------------------------------------
// fc projection, both node types in one launch: tiled fp32 GEMM 64x64, BK=16
// ---------------------------------------------------------------------------
#define T0_TILES 469  // ceil(30000/64)
#define T1_TILES 313  // ceil(20000/64)
__global__ __launch_bounds__(256) void fc_gemm(const float* __restrict__ A0,
                                               const float* __restrict__ B0,
                                               const float* __restrict__ bias0,
                                               const float* __restrict__ A1,
                                               const float* __restrict__ B1,
                                               const float* __restrict__ bias1,
                                               _Float16* __restrict__ Cb) {
    __shared__ float As[16][68];
    __shared__ float Bs[16][68];
    int bid = blockIdx.x;
    const float* A; const float* B; const float* bias;
    int M, K, row_off, m0;
    if (bid < T0_TILES) { A = A0; B = B0; bias = bias0; M = 30000; K = 256; row_off = 0;     m0 = bid * 64; }
    else                { A = A1; B = B1; bias = bias1; M = 20000; K = 128; row_off = 30000; m0 = (bid - T0_TILES) * 64; }
    int tid = threadIdx.x;
    int tx = tid & 15, ty = tid >> 4;
    float acc[4][4] = {};
    int arow = tid >> 2;
    int akq  = (tid & 3) * 4;
    int brow = tid >> 4;
    int bcol = (tid & 15) * 4;
    for (int k0 = 0; k0 < K; k0 += 16) {
        int m = m0 + arow;
        float4 av = make_float4(0.f, 0.f, 0.f, 0.f);
        if (m < M) av = *(const float4*)(A + (size_t)m * K + k0 + akq);
        As[akq + 0][arow] = av.x; As[akq + 1][arow] = av.y;
        As[akq + 2][arow] = av.z; As[akq + 3][arow] = av.w;
        float4 bv = *(const float4*)(B + (size_t)(k0 + brow) * 64 + bcol);
        *(float4*)(&Bs[brow][bcol]) = bv;
        __syncthreads();
#pragma unroll
        for (int k = 0; k < 16; k++) {
            float4 a = *(const float4*)(&As[k][ty * 4]);
            float4 b = *(const float4*)(&Bs[k][tx * 4]);
            float av4[4] = {a.x, a.y, a.z, a.w};
            float bv4[4] = {b.x, b.y, b.z, b.w};
#pragma unroll
            for (int i = 0; i < 4; i++)
#pragma unroll
                for (int j = 0; j < 4; j++) acc[i][j] += av4[i] * bv4[j];
        }
        __syncthreads();
    }
#pragma unroll
    for (int i = 0; i < 4; i++) {
        int m = m0 + ty * 4 + i;
        if (m < M) {
#pragma unroll
            for (int j = 0; j < 4; j++) {
                int col = tx * 4 + j;
                Cb[(size_t)(row_off + m) * 64 + col] = (_Float16)(acc[i][j] + bias[col]);
            }
        }
    }
}

// ---------------------------------------------------------------------------
// CSR build: count -> parallel scan (3 kernels) -> scatter
// ---------------------------------------------------------------------------
#define NBLK_SCAN 196  // ceil(50000/256)

__global__ void count_kernel(const int* __restrict__ dst, int* __restrict__ cnt) {
    int t = blockIdx.x * blockDim.x + threadIdx.x;
    if (t < N_EDGES) atomicAdd(&cnt[dst[t]], 1);
}

__global__ void scan_part(const int* __restrict__ cnt, int* __restrict__ part) {
    __shared__ int s[256];
    int i = blockIdx.x * 256 + threadIdx.x;
    s[threadIdx.x] = (i < N_NODES) ? cnt[i] : 0;
    __syncthreads();
    for (int off = 128; off; off >>= 1) {
        if (threadIdx.x < off) s[threadIdx.x] += s[threadIdx.x + off];
        __syncthreads();
    }
    if (threadIdx.x == 0) part[blockIdx.x] = s[0];
}

__global__ void scan_offs(int* __restrict__ part) {
    __shared__ int s[256];
    int tid = threadIdx.x;
    int v = (tid < NBLK_SCAN) ? part[tid] : 0;
    s[tid] = v;
    __syncthreads();
    for (int off = 1; off < 256; off <<= 1) {
        int x = (tid >= off) ? s[tid - off] : 0;
        __syncthreads();
        s[tid] += x;
        __syncthreads();
    }
    if (tid < NBLK_SCAN) part[tid] = s[tid] - v;  // exclusive
}

__global__ void scan_apply(const int* __restrict__ cnt, const int* __restrict__ part,
                           int* __restrict__ rp, int* __restrict__ cur) {
    __shared__ int s[256];
    int tid = threadIdx.x;
    int i = blockIdx.x * 256 + tid;
    int v = (i < N_NODES) ? cnt[i] : 0;
    s[tid] = v;
    __syncthreads();
    for (int off = 1; off < 256; off <<= 1) {
        int x = (tid >= off) ? s[tid - off] : 0;
        __syncthreads();
        s[tid] += x;
        __syncthreads();
    }
    if (i < N_NODES) {
        int excl = s[tid] - v + part[blockIdx.x];
        rp[i] = excl; cur[i] = excl;
    }
    if (i == 0) rp[N_NODES] = N_EDGES;
}

__global__ void scatter_kernel(const int* __restrict__ src, const int* __restrict__ dst,
                               int* __restrict__ cursor, int* __restrict__ src_sorted) {
    int t = blockIdx.x * blockDim.x + threadIdx.x;
    if (t >= N_EDGES) return;
    int pos = atomicAdd(&cursor[dst[t]], 1);
    src_sorted[pos] = src[t];
}

// ---------------------------------------------------------------------------
// weight transpose+cast (both weights, one launch): Wt[n][k] = f16(W[k][n])
// ---------------------------------------------------------------------------
__global__ void wtrans(const float* __restrict__ W0, const float* __restrict__ W1,
                       _Float16* __restrict__ W0t, _Float16* __restrict__ W1t) {
    int t = blockIdx.x * blockDim.x + threadIdx.x;
    if (t < 64 * 512) {
        int n = t >> 6, k = t & 63;
        W0t[t] = (_Float16)W0[k * 512 + n];
    } else {
        int u = t - 64 * 512;
        if (u >= 512 * 512) return;
        int n = u >> 9, k = u & 511;
        W1t[u] = (_Float16)W1[k * 512 + n];
    }
}

// ---------------------------------------------------------------------------
// Wide f16 MFMA GEMM: 128x256 tile, 512 threads (8 waves), BK=32, XOR-4
// kgroup swizzle. XCD co-location: same-y tiles get bid congruent mod 8 so
// both n-tiles sharing an A slice land on one XCD's L2 (round-robin heuristic;
// affects locality only, never correctness).
// Fused epilogue: el/er per (row, head); each wave's 64 cols = 1 head.
// N fixed at 512 (HD).
// ---------------------------------------------------------------------------
__global__ __launch_bounds__(512) void gemm_mfma_wide(const _Float16* __restrict__ A,
                                                      const _Float16* __restrict__ Bt,
                                                      _Float16* __restrict__ Cb,
                                                      const float* __restrict__ al,
                                                      const float* __restrict__ ar,
                                                      float* __restrict__ el,
                                                      float* __restrict__ er,
                                                      int M, int K) {
    __shared__ _Float16 Asl[128 * 32];
    __shared__ _Float16 Bsl[256 * 32];
    int bid = blockIdx.x;
    int k8 = bid & 7, jj = bid >> 3;
    int y = k8 + 8 * (jj >> 1);
    if (y >= YTILES) return;
    int m0 = y * 128;
    int n0 = (jj & 1) * 256;
    int t = threadIdx.x;
    int lane = t & 63;
    int w = t >> 6;                       // 0..7
    int wm = (w & 1) * 64, wn = (w >> 1) * 64;   // wn 0..192
    int l15 = lane & 15, quad = lane >> 4;
    f32x4 acc[4][4];
#pragma unroll
    for (int i = 0; i < 4; i++)
#pragma unroll
        for (int j = 0; j < 4; j++) acc[i][j] = (f32x4){0.f, 0.f, 0.f, 0.f};

    // staging: A 8KB (1 chunk/thread), B 16KB (2 chunks/thread); row = 64B
    int fbA = t * 16;
    int rowA = fbA >> 6, kgA = ((fbA >> 4) & 3) ^ (rowA & 3);
    int fbB0 = t * 16;
    int fbB1 = fbB0 + 8192;
    int rowB0 = fbB0 >> 6, kgB0 = ((fbB0 >> 4) & 3) ^ (rowB0 & 3);
    int rowB1 = fbB1 >> 6, kgB1 = ((fbB1 >> 4) & 3) ^ (rowB1 & 3);

    for (int k0 = 0; k0 < K; k0 += 32) {
        GLD_LDS16(A + (size_t)(m0 + rowA) * K + k0 + kgA * 8, (char*)Asl + fbA);
        GLD_LDS16(Bt + (size_t)(n0 + rowB0) * K + k0 + kgB0 * 8, (char*)Bsl + fbB0);
        GLD_LDS16(Bt + (size_t)(n0 + rowB1) * K + k0 + kgB1 * 8, (char*)Bsl + fbB1);
        __syncthreads();
        f16x8 af[4], bfr[4];
#pragma unroll
        for (int i = 0; i < 4; i++) {
            int r = wm + i * 16 + l15;
            int kg = quad ^ (r & 3);
            af[i] = *(const f16x8*)(Asl + r * 32 + kg * 8);
        }
#pragma unroll
        for (int j = 0; j < 4; j++) {
            int r = wn + j * 16 + l15;
            int kg = quad ^ (r & 3);
            bfr[j] = *(const f16x8*)(Bsl + r * 32 + kg * 8);
        }
#pragma unroll
        for (int i = 0; i < 4; i++)
#pragma unroll
            for (int j = 0; j < 4; j++)
                acc[i][j] = __builtin_amdgcn_mfma_f32_16x16x32_f16(af[i], bfr[j], acc[i][j], 0, 0, 0);
        __syncthreads();
    }
    // C/D layout: col = l15, row = quad*4 + reg  [m89/m91 verified]
#pragma unroll
    for (int i = 0; i < 4; i++) {
        int rbase = m0 + wm + i * 16 + quad * 4;
#pragma unroll
        for (int j = 0; j < 4; j++) {
            int col = n0 + wn + j * 16 + l15;
#pragma unroll
            for (int r = 0; r < 4; r++) {
                int row = rbase + r;
                if (row < M) Cb[(size_t)row * HD + col] = (_Float16)acc[i][j][r];
            }
        }
    }
    // fused el/er: this wave's 64 cols = head h
    int h = (n0 + wn) >> 6;
    float alv[4], arv[4];
#pragma unroll
    for (int j = 0; j < 4; j++) {
        alv[j] = al[h * 64 + j * 16 + l15];
        arv[j] = ar[h * 64 + j * 16 + l15];
    }
#pragma unroll
    for (int i = 0; i < 4; i++) {
#pragma unroll
        for (int r = 0; r < 4; r++) {
            float sl = 0.f, sr = 0.f;
#pragma unroll
            for (int j = 0; j < 4; j++) {
                float v = acc[i][j][r];
                sl += v * alv[j]; sr += v * arv[j];
            }
#pragma unroll
            for (int mk = 1; mk < 16; mk <<= 1) {
                sl += __shfl_xor(sl, mk);
                sr += __shfl_xor(sr, mk);
            }
            int row = m0 + wm + i * 16 + quad * 4 + r;
            if (l15 == 0 && row < M) {
                el[row * HEADS + h] = sl;
                er[row * HEADS + h] = sr;
            }
        }
    }
}

// ---------------------------------------------------------------------------
// Fused edge softmax + aggregation, wave per dst node. Wave-private LDS
// handoff (no block barrier). Phase B: 4x-unrolled gather, packed f16 FMA.
// ---------------------------------------------------------------------------
__global__ __launch_bounds__(256) void attn_agg(
        const int* __restrict__ rp, const int* __restrict__ srcs,
        const float* __restrict__ el, const float* __restrict__ er,
        const _Float16* __restrict__ feat, const float* __restrict__ bias,
        _Float16* __restrict__ out) {
    __shared__ float aS[4][592];   // [0..575] alpha (p*9+h), [576..583] inv, [584..591] m
    __shared__ int   sS[4][64];
    int lane = threadIdx.x & 63;
    int w    = threadIdx.x >> 6;
    int n    = blockIdx.x * 4 + w;
    int s0 = rp[n], s1 = rp[n + 1];
    int deg = s1 - s0;
    float er8[8];
    {
        f32x4 a = *(const f32x4*)(er + (size_t)n * 8);
        f32x4 b = *(const f32x4*)(er + (size_t)n * 8 + 4);
        er8[0]=a[0]; er8[1]=a[1]; er8[2]=a[2]; er8[3]=a[3];
        er8[4]=b[0]; er8[5]=b[1]; er8[6]=b[2]; er8[7]=b[3];
    }
    bool fast = (deg <= 64);
    if (fast) {
        bool act = lane < deg;
        int sp = act ? srcs[s0 + lane] : 0;
        sS[w][lane] = sp;
        f32x4 ea = {0.f,0.f,0.f,0.f}, eb = {0.f,0.f,0.f,0.f};
        if (act) {
            ea = *(const f32x4*)(el + (size_t)sp * 8);
            eb = *(const f32x4*)(el + (size_t)sp * 8 + 4);
        }
        float e8[8] = {ea[0],ea[1],ea[2],ea[3],eb[0],eb[1],eb[2],eb[3]};
#pragma unroll
        for (int h = 0; h < 8; h++) {
            float e = e8[h] + er8[h];
            e = e > 0.f ? e : 0.2f * e;
            e8[h] = act ? e : -1e30f;
        }
#pragma unroll
        for (int h = 0; h < 8; h++) {
            float mm = e8[h];
#pragma unroll
            for (int mk = 1; mk < 64; mk <<= 1) mm = fmaxf(mm, __shfl_xor(mm, mk));
            float pv = act ? __expf(e8[h] - mm) : 0.f;
            float ss = pv;
#pragma unroll
            for (int mk = 1; mk < 64; mk <<= 1) ss += __shfl_xor(ss, mk);
            aS[w][lane * 9 + h] = pv * (1.f / fmaxf(ss, 1e-9f));  // pre-scaled alpha
        }
    } else {
        float m8[8], s8[8];
#pragma unroll
        for (int h = 0; h < 8; h++) { m8[h] = -1e30f; s8[h] = 0.f; }
        for (int base = s0; base < s1; base += 64) {
            bool act = base + lane < s1;
            int sp = act ? srcs[base + lane] : 0;
            f32x4 ea = {0.f,0.f,0.f,0.f}, eb = {0.f,0.f,0.f,0.f};
            if (act) {
                ea = *(const f32x4*)(el + (size_t)sp * 8);
                eb = *(const f32x4*)(el + (size_t)sp * 8 + 4);
            }
            float ev[8] = {ea[0],ea[1],ea[2],ea[3],eb[0],eb[1],eb[2],eb[3]};
#pragma unroll
            for (int h = 0; h < 8; h++) {
                float e = ev[h] + er8[h];
                e = e > 0.f ? e : 0.2f * e;
                e = act ? e : -1e30f;
                float cm = e;
#pragma unroll
                for (int mk = 1; mk < 64; mk <<= 1) cm = fmaxf(cm, __shfl_xor(cm, mk));
                float nm = fmaxf(m8[h], cm);
                float pv = act ? __expf(e - nm) : 0.f;
#pragma unroll
                for (int mk = 1; mk < 64; mk <<= 1) pv += __shfl_xor(pv, mk);
                s8[h] = s8[h] * __expf(m8[h] - nm) + pv;
                m8[h] = nm;
            }
        }
        if (lane == 0) {
#pragma unroll
            for (int h = 0; h < 8; h++) {
                aS[w][576 + h] = 1.f / fmaxf(s8[h], 1e-9f);
                aS[w][584 + h] = m8[h];
            }
        }
    }
    // wave-private LDS handoff (lockstep wave + compiler lgkmcnt ordering)
    __builtin_amdgcn_wave_barrier();
    int hh = lane >> 3, d0 = (lane & 7) * 8;   // lane*8 = hh*64 + d0
    h8v z = {(_Float16)0, (_Float16)0, (_Float16)0, (_Float16)0,
             (_Float16)0, (_Float16)0, (_Float16)0, (_Float16)0};
    h8v acc0 = z, acc1 = z, acc2 = z, acc3 = z;
    const _Float16* colbase = feat + hh * 64 + d0;
    if (fast) {
        int p = 0;
        for (; p + 4 <= deg; p += 4) {
            int spa = sS[w][p],     spb = sS[w][p + 1];
            int spc = sS[w][p + 2], spd = sS[w][p + 3];
            _Float16 aa = (_Float16)aS[w][p * 9 + hh];
            _Float16 ab = (_Float16)aS[w][(p + 1) * 9 + hh];
            _Float16 ac = (_Float16)aS[w][(p + 2) * 9 + hh];
            _Float16 ad = (_Float16)aS[w][(p + 3) * 9 + hh];
            h8v fa = *(const h8v*)(colbase + (size_t)spa * HD);
            h8v fb = *(const h8v*)(colbase + (size_t)spb * HD);
            h8v fc = *(const h8v*)(colbase + (size_t)spc * HD);
            h8v fd = *(const h8v*)(colbase + (size_t)spd * HD);
            h8v a8a = {aa, aa, aa, aa, aa, aa, aa, aa};
            h8v a8b = {ab, ab, ab, ab, ab, ab, ab, ab};
            h8v a8c = {ac, ac, ac, ac, ac, ac, ac, ac};
            h8v a8d = {ad, ad, ad, ad, ad, ad, ad, ad};
            acc0 += a8a * fa;
            acc1 += a8b * fb;
            acc2 += a8c * fc;
            acc3 += a8d * fd;
        }
        for (; p < deg; p++) {
            int sp = sS[w][p];
            _Float16 ah = (_Float16)aS[w][p * 9 + hh];
            h8v a8 = {ah, ah, ah, ah, ah, ah, ah, ah};
            h8v f = *(const h8v*)(colbase + (size_t)sp * HD);
            acc0 += a8 * f;
        }
    } else {
        float inv_l = aS[w][576 + hh];
        float m_l   = aS[w][584 + hh];
        float ern_l = er[(size_t)n * 8 + hh];
        for (int p = s0; p < s1; p++) {
            int sp = srcs[p];
            float e = el[(size_t)sp * 8 + hh] + ern_l;
            e = e > 0.f ? e : 0.2f * e;
            _Float16 ah = (_Float16)(__expf(e - m_l) * inv_l);
            h8v a8 = {ah, ah, ah, ah, ah, ah, ah, ah};
            h8v f = *(const h8v*)(colbase + (size_t)sp * HD);
            acc0 += a8 * f;
        }
    }
    acc0 += acc1; acc2 += acc3; acc0 += acc2;
    float4 b0v = *(const float4*)(bias + lane * 8);
    float4 b1v = *(const float4*)(bias + lane * 8 + 4);
    float bb[8] = {b0v.x,b0v.y,b0v.z,b0v.w,b1v.x,b1v.y,b1v.z,b1v.w};
    h8v o;
#pragma unroll
    for (int j = 0; j < 8; j++) {
        float x = (float)acc0[j] + bb[j];
        x = x > 0.f ? x : __expf(x) - 1.f;
        o[j] = (_Float16)x;
    }
    *(h8v*)(out + (size_t)n * HD + lane * 8) = o;
}

// ---------------------------------------------------------------------------
// layer 2 GEMM (N=10) from f16 A, fused el2/er2 epilogue
// ---------------------------------------------------------------------------
__global__ __launch_bounds__(256) void gemm_n10v2(
        const _Float16* __restrict__ A, const float* __restrict__ B,
        const float* __restrict__ al2, const float* __restrict__ ar2,
        float* __restrict__ C, float* __restrict__ el, float* __restrict__ er) {
    __shared__ float Bs[512 * 11];
    int t = threadIdx.x;
    for (int i = t; i < 512 * NCLS; i += 256) {
        int k = i / NCLS, c = i - k * NCLS;
        Bs[k * 11 + c] = B[i];
    }
    __syncthreads();
    int lane = t & 63;
    int m = blockIdx.x * 4 + (t >> 6);
    float acc[NCLS];
#pragma unroll
    for (int c = 0; c < NCLS; c++) acc[c] = 0.f;
    const _Float16* a = A + (size_t)m * HD;
#pragma unroll
    for (int j = 0; j < 8; j++) {
        float av = (float)a[j * 64 + lane];
        const float* br = Bs + (j * 64 + lane) * 11;
#pragma unroll
        for (int c = 0; c < NCLS; c++) acc[c] += av * br[c];
    }
#pragma unroll
    for (int c = 0; c < NCLS; c++)
#pragma unroll
        for (int mk = 1; mk < 64; mk <<= 1) acc[c] += __shfl_xor(acc[c], mk);
    if (lane == 0) {
        float e1 = 0.f, e2 = 0.f;
#pragma unroll
        for (int c = 0; c < NCLS; c++) { e1 += acc[c] * al2[c]; e2 += acc[c] * ar2[c]; }
        el[m] = e1; er[m] = e2;
#pragma unroll
        for (int c = 0; c < NCLS; c++) C[(size_t)m * NCLS + c] = acc[c];
    }
}

// ---------------------------------------------------------------------------
// layer 2 fused softmax+aggregation (H=1, D=10), wave per dst node
// ---------------------------------------------------------------------------
__global__ __launch_bounds__(256) void attn2_agg2(
        const int* __restrict__ rp, const int* __restrict__ srcs,
        const float* __restrict__ el, const float* __restrict__ er,
        const float* __restrict__ feat2, const float* __restrict__ b2,
        float* __restrict__ out) {
    int lane = threadIdx.x & 63;
    int n = blockIdx.x * 4 + (threadIdx.x >> 6);
    int s0 = rp[n], s1 = rp[n + 1], deg = s1 - s0;
    float ern = er[n];
    float facc[NCLS];
#pragma unroll
    for (int c = 0; c < NCLS; c++) facc[c] = 0.f;
    if (deg <= 64) {
        bool act = lane < deg;
        int sp = act ? srcs[s0 + lane] : 0;
        float e = act ? el[sp] + ern : 0.f;
        e = e > 0.f ? e : 0.2f * e;
        if (!act) e = -1e30f;
        float mm = e;
#pragma unroll
        for (int mk = 1; mk < 64; mk <<= 1) mm = fmaxf(mm, __shfl_xor(mm, mk));
        float pv = act ? __expf(e - mm) : 0.f;
        float ss = pv;
#pragma unroll
        for (int mk = 1; mk < 64; mk <<= 1) ss += __shfl_xor(ss, mk);
        float a = pv / fmaxf(ss, 1e-9f);
        if (act) {
#pragma unroll
            for (int c = 0; c < NCLS; c++) facc[c] = a * feat2[(size_t)sp * NCLS + c];
        }
    } else {
        float mm = -1e30f, ssum = 0.f;
        for (int base = s0; base < s1; base += 64) {
            bool act = base + lane < s1;
            int sp = act ? srcs[base + lane] : 0;
            float e = act ? el[sp] + ern : 0.f;
            e = e > 0.f ? e : 0.2f * e;
            if (!act) e = -1e30f;
            float cm = e;
#pragma unroll
            for (int mk = 1; mk < 64; mk <<= 1) cm = fmaxf(cm, __shfl_xor(cm, mk));
            float nm = fmaxf(mm, cm);
            float pv = act ? __expf(e - nm) : 0.f;
#pragma unroll
            for (int mk = 1; mk < 64; mk <<= 1) pv += __shfl_xor(pv, mk);
            ssum = ssum * __expf(mm - nm) + pv;
            mm = nm;
        }
        float inv = 1.f / fmaxf(ssum, 1e-9f);
        for (int base = s0; base < s1; base += 64) {
            bool act = base + lane < s1;
            int sp = act ? srcs[base + lane] : 0;
            float e = act ? el[sp] + ern : 0.f;
            e = e > 0.f ? e : 0.2f * e;
            float a = act ? __expf(e - mm) * inv : 0.f;
            if (act) {
#pragma unroll
                for (int c = 0; c < NCLS; c++) facc[c] += a * feat2[(size_t)sp * NCLS + c];
            }
        }
    }
#pragma unroll
    for (int c = 0; c < NCLS; c++)
#pragma unroll
        for (int mk = 1; mk < 64; mk <<= 1) facc[c] += __shfl_xor(facc[c], mk);
    if (lane == 0) {
#pragma unroll
        for (int c = 0; c < NCLS; c++) out[(size_t)n * NCLS + c] = facc[c] + b2[c];
    }
}

// ---------------------------------------------------------------------------
extern "C" void kernel_launch(void* const* d_in, const int* in_sizes, int n_in,
                              void* d_out, int out_size, void* d_ws, size_t ws_size,
                              hipStream_t stream) {
    const float* feat0 = (const float*)d_in[0];
    const float* feat1 = (const float*)d_in[1];
    const float* fc0_w = (const float*)d_in[2];
    const float* fc0_b = (const float*)d_in[3];
    const float* fc1_w = (const float*)d_in[4];
    const float* fc1_b = (const float*)d_in[5];
    const float* W0    = (const float*)d_in[6];
    const float* al0   = (const float*)d_in[7];
    const float* ar0   = (const float*)d_in[8];
    const float* b0    = (const float*)d_in[9];
    const float* W1    = (const float*)d_in[10];
    const float* al1   = (const float*)d_in[11];
    const float* ar1   = (const float*)d_in[12];
    const float* b1    = (const float*)d_in[13];
    const float* W2    = (const float*)d_in[14];
    const float* al2   = (const float*)d_in[15];
    const float* ar2   = (const float*)d_in[16];
    const float* b2    = (const float*)d_in[17];
    const int* eidx    = (const int*)d_in[18];
    const int* src = eidx;
    const int* dst = eidx + N_EDGES;
    float* out = (float*)d_out;

    char* ws = (char*)d_ws;
    size_t off = 0;
    auto alloc = [&](size_t bytes) { size_t o = off; off = (off + bytes + 255) & ~(size_t)255; return o; };

    _Float16* featA = (_Float16*)(ws + alloc((size_t)M_PAD * HD * 2));
    _Float16* aggh  = (_Float16*)(ws + alloc((size_t)M_PAD * HD * 2));
    _Float16* h0h   = (_Float16*)(ws + alloc((size_t)M_PAD * 64 * 2));
    float*    feat2 = (float*)(ws + alloc((size_t)N_NODES * NCLS * 4));
    float*    el    = (float*)(ws + alloc((size_t)N_NODES * HEADS * 4));
    float*    er    = (float*)(ws + alloc((size_t)N_NODES * HEADS * 4));
    float*    el2   = (float*)(ws + alloc((size_t)N_NODES * 4));
    float*    er2   = (float*)(ws + alloc((size_t)N_NODES * 4));
    int*      cnt   = (int*)  (ws + alloc((size_t)N_NODES * 4));
    int*      rp    = (int*)  (ws + alloc((size_t)(N_NODES + 1) * 4));
    int*      cur   = (int*)  (ws + alloc((size_t)N_NODES * 4));
    int*      srcs  = (int*)  (ws + alloc((size_t)N_EDGES * 4));
    int*      part  = (int*)  (ws + alloc(1024));
    _Float16* W0t   = (_Float16*)(ws + alloc(512 * 64 * 2));
    _Float16* W1t   = (_Float16*)(ws + alloc(512 * 512 * 2));

    // --- fc projection (both types, one launch) ---
    fc_gemm<<<T0_TILES + T1_TILES, 256, 0, stream>>>(feat0, fc0_w, fc0_b,
                                                     feat1, fc1_w, fc1_b, h0h);
    // --- weight transpose+cast (one launch) ---
    wtrans<<<(64 * 512 + 512 * 512 + 255) / 256, 256, 0, stream>>>(W0, W1, W0t, W1t);

    // --- CSR build ---
    hipMemsetAsync(cnt, 0, N_NODES * sizeof(int), stream);
    count_kernel<<<(N_EDGES + 255) / 256, 256, 0, stream>>>(dst, cnt);
    scan_part<<<NBLK_SCAN, 256, 0, stream>>>(cnt, part);
    scan_offs<<<1, 256, 0, stream>>>(part);
    scan_apply<<<NBLK_SCAN, 256, 0, stream>>>(cnt, part, rp, cur);
    scatter_kernel<<<(N_EDGES + 255) / 256, 256, 0, stream>>>(src, dst, cur, srcs);

    int ggrid = 8 * 98;  // XCD-decoded 1-D grid: covers 391 y-tiles x 2 n-tiles

    // --- layer 0 ---
    gemm_mfma_wide<<<ggrid, 512, 0, stream>>>(h0h, W0t, featA, al0, ar0, el, er,
                                              N_NODES, 64);
    attn_agg<<<N_NODES / 4, 256, 0, stream>>>(rp, srcs, el, er, featA, b0, aggh);

    // --- layer 1 ---
    gemm_mfma_wide<<<ggrid, 512, 0, stream>>>(aggh, W1t, featA, al1, ar1, el, er,
                                              N_NODES, HD);
    attn_agg<<<N_NODES / 4, 256, 0, stream>>>(rp, srcs, el, er, featA, b1, aggh);

    // --- layer 2 ---
    gemm_n10v2<<<N_NODES / 4, 256, 0, stream>>>(aggh, W2, al2, ar2, feat2, el2, er2);
    attn2_agg2<<<N_NODES / 4, 256, 0, stream>>>(rp, srcs, el2, er2, feat2, b2, out);
}